// Round 3
// baseline (412.251 us; speedup 1.0000x reference)
//
#include <hip/hip_runtime.h>
#include <hip/hip_bf16.h>

// Problem: B=16, C=256, H=W=64 -> N=4096.
// ref: attn = sum_s softmax(max-E_s) over last dim, E_s = Q K_s^T (reduce over N)
//      out  = gamma * (conv_w @ (attn @ Q) + bias) + x
// fused as: M = conv_w @ attn  (tiny GEMM), P = M @ Q, out = gamma*(P+bias)+x
//
// v4 changes vs v3 (406 us):
//  - energy_kernel (77.8 us, MfmaUtil 12.8%, VALUBusy 15.4%, 72% idle ->
//    latency-bound on serial reg-staging) and pmq_kernel converted to
//    direct-to-LDS staging via __builtin_amdgcn_global_load_lds width=16
//    (the m93->m97 ladder step: 517->874 TF on this exact 128^2 2-barrier
//    structure). LDS tiles are linear [128][64] (global_load_lds requires
//    contiguous wave-order destinations; padding would corrupt). The 16-way
//    ds_read bank aliasing this reintroduces is accepted (m97 measured 874 TF
//    with it; the swizzle fix is null outside 8-phase schedules).

#define B_ 16
#define C_ 256
#define N_ 4096
#define KSPLIT 4
#define KCHUNK (N_ / KSPLIT)   // 1024

#define MODE_BF16 0
#define MODE_F32  1

typedef __bf16 bf16_t;
typedef bf16_t bf16x8 __attribute__((ext_vector_type(8)));
typedef float  f32x4  __attribute__((ext_vector_type(4)));

#define MFMA(a, b, c) __builtin_amdgcn_mfma_f32_16x16x32_bf16(a, b, c, 0, 0, 0)

// Direct global->LDS async copy, 16 B per lane. LDS dest is wave-uniform
// base + lane*16; global src is per-lane.
#define GLDS(gaddr, laddr)                                                   \
  __builtin_amdgcn_global_load_lds(                                          \
      (const __attribute__((address_space(1))) void*)(gaddr),                \
      (__attribute__((address_space(3))) void*)(laddr), 16, 0, 0)

// Scratch (module-load allocated; no ws_size dependence; graph-safe).
__device__ int    g_mode;
__device__ bf16_t g_in[3][(size_t)B_ * C_ * N_];   // canonical x,y,z (100.7 MB)
__device__ bf16_t g_qT[(size_t)B_ * N_ * C_];      // x transposed [b][n][c] (33.5 MB)
__device__ bf16_t g_cw[C_ * C_];
__device__ float  g_cb[C_];
__device__ float  g_gamma;
__device__ float  g_Ep[(size_t)KSPLIT * 3 * B_ * C_ * C_];  // partial E, 50.3 MB
__device__ bf16_t g_attnT[(size_t)B_ * C_ * C_];
__device__ bf16_t g_M[(size_t)B_ * C_ * C_];
__device__ bf16_t g_P[(size_t)B_ * C_ * N_];       // P = M @ Q (33.5 MB)

// ---------------------------------------------------------------------------
// Kernel 0: dtype sniff. fp32 N(0,1) data -> abs bits <= ~0x40C00000.
// bf16 pairs misread as fp32 -> exponent field from bf16 payload bits,
// values ~1e37 almost surely. Threshold 1024.0f separates cleanly.
// ---------------------------------------------------------------------------
__global__ __launch_bounds__(256) void detect_kernel(const float* __restrict__ xf)
{
  __shared__ unsigned red[256];
  const int t = threadIdx.x;
  unsigned m = 0;
  for (int i = t; i < 4096; i += 256)
    m = max(m, __float_as_uint(xf[i]) & 0x7fffffffu);
  red[t] = m;
  __syncthreads();
  for (int s = 128; s > 0; s >>= 1) {
    if (t < s) red[t] = max(red[t], red[t + s]);
    __syncthreads();
  }
  if (t == 0) g_mode = (red[0] > 0x44800000u) ? MODE_BF16 : MODE_F32;
}

// ---------------------------------------------------------------------------
// Kernel 0b: canonicalize y,z into bf16 staging. grid (8192, 2).
// ---------------------------------------------------------------------------
__global__ __launch_bounds__(256) void convert_big(
    const void* __restrict__ y, const void* __restrict__ z)
{
  const void* src = blockIdx.y == 0 ? y : z;
  bf16_t* dst = g_in[1 + blockIdx.y];
  const size_t idx = ((size_t)blockIdx.x * 256 + threadIdx.x) * 8;
  if (g_mode == MODE_F32) {
    const float* s = (const float*)src + idx;
    float4 a = *(const float4*)s;
    float4 b = *(const float4*)(s + 4);
    bf16x8 v;
    v[0] = (bf16_t)a.x; v[1] = (bf16_t)a.y; v[2] = (bf16_t)a.z; v[3] = (bf16_t)a.w;
    v[4] = (bf16_t)b.x; v[5] = (bf16_t)b.y; v[6] = (bf16_t)b.z; v[7] = (bf16_t)b.w;
    *(bf16x8*)(dst + idx) = v;
  } else {
    *(bf16x8*)(dst + idx) = *(const bf16x8*)((const bf16_t*)src + idx);
  }
}

// ---------------------------------------------------------------------------
// Kernel 0d: canonicalize x into bf16 AND materialize x^T [b][n][c] in bf16.
// 64x64 tiles via LDS. grid (N/64, C/64, B).
// ---------------------------------------------------------------------------
__global__ __launch_bounds__(256) void convert_xT(const void* __restrict__ x)
{
  __shared__ bf16_t Ts[64][72];   // [c_local][n_local], padded
  const int t  = threadIdx.x;
  const int r  = t >> 3;          // 0..31
  const int co = (t & 7) * 8;     // 0..56
  const int n0 = blockIdx.x * 64;
  const int c0 = blockIdx.y * 64;
  const int b  = blockIdx.z;
  const size_t base = (size_t)b * C_ * N_;

  bf16x8 v[2];
  if (g_mode == MODE_F32) {
#pragma unroll
    for (int p = 0; p < 2; ++p) {
      const float* s = (const float*)x + base + (size_t)(c0 + r + p * 32) * N_ + n0 + co;
      float4 a = *(const float4*)s;
      float4 b4 = *(const float4*)(s + 4);
      bf16x8 w;
      w[0] = (bf16_t)a.x; w[1] = (bf16_t)a.y; w[2] = (bf16_t)a.z; w[3] = (bf16_t)a.w;
      w[4] = (bf16_t)b4.x; w[5] = (bf16_t)b4.y; w[6] = (bf16_t)b4.z; w[7] = (bf16_t)b4.w;
      v[p] = w;
    }
  } else {
#pragma unroll
    for (int p = 0; p < 2; ++p)
      v[p] = *(const bf16x8*)((const bf16_t*)x + base + (size_t)(c0 + r + p * 32) * N_ + n0 + co);
  }

  // write-through normal bf16 staging + stage tile in LDS
#pragma unroll
  for (int p = 0; p < 2; ++p) {
    *(bf16x8*)(g_in[0] + base + (size_t)(c0 + r + p * 32) * N_ + n0 + co) = v[p];
    *(bf16x8*)(&Ts[r + p * 32][co]) = v[p];
  }
  __syncthreads();

  // write transposed rows: QT[b][n0+n][c0+co .. +7]
#pragma unroll
  for (int p = 0; p < 2; ++p) {
    const int n = r + p * 32;
    bf16x8 w;
#pragma unroll
    for (int j = 0; j < 8; ++j) w[j] = Ts[co + j][n];
    *(bf16x8*)(g_qT + (size_t)b * N_ * C_ + (size_t)(n0 + n) * C_ + c0 + co) = w;
  }
}

// ---------------------------------------------------------------------------
// Kernel 0c: canonicalize conv_w (bf16), conv_b + gamma (fp32). 1 block.
// ---------------------------------------------------------------------------
__global__ __launch_bounds__(256) void convert_params(
    const void* __restrict__ cw, const void* __restrict__ cb,
    const void* __restrict__ gm)
{
  const int t = threadIdx.x;
  if (g_mode == MODE_F32) {
    for (int i = t * 8; i < C_ * C_; i += 256 * 8) {
      const float* s = (const float*)cw + i;
      float4 a = *(const float4*)s;
      float4 b = *(const float4*)(s + 4);
      bf16x8 v;
      v[0] = (bf16_t)a.x; v[1] = (bf16_t)a.y; v[2] = (bf16_t)a.z; v[3] = (bf16_t)a.w;
      v[4] = (bf16_t)b.x; v[5] = (bf16_t)b.y; v[6] = (bf16_t)b.z; v[7] = (bf16_t)b.w;
      *(bf16x8*)(g_cw + i) = v;
    }
    if (t < C_) g_cb[t] = ((const float*)cb)[t];
    if (t == 0) g_gamma = ((const float*)gm)[0];
  } else {
    for (int i = t * 8; i < C_ * C_; i += 256 * 8)
      *(bf16x8*)(g_cw + i) = *(const bf16x8*)((const bf16_t*)cw + i);
    if (t < C_) g_cb[t] = (float)((const bf16_t*)cb)[t];
    if (t == 0) g_gamma = (float)((const bf16_t*)gm)[0];
  }
}

// ---------------------------------------------------------------------------
// Kernel 1: Ep[kc][s][b][c][d] = sum_{n in chunk} Q[b,c,n] * Ksrc_s[b,d,n]
// 128x128 tile, 4 waves of 64x64, BK=64, direct-to-LDS (global_load_lds x16B)
// staged NT GEMM, K split x4. grid (4 tiles * KSPLIT, 3, B).
// LDS is linear [128][64]: global_load_lds writes wave-uniform-base+lane*16,
// so no row padding is possible.
// ---------------------------------------------------------------------------
__global__ __launch_bounds__(256) void energy_kernel()
{
  const int tile = blockIdx.x & 3;   // 0..3
  const int kc   = blockIdx.x >> 2;  // 0..3
  const int s    = blockIdx.y;       // 0..2
  const int b    = blockIdx.z;       // 0..15

  const bf16_t* q = g_in[0] + (size_t)b * C_ * N_;
  const bf16_t* k = g_in[s] + (size_t)b * C_ * N_;

  const int tile_m = (tile & 1) * 128;
  const int tile_d = (tile >> 1) * 128;

  __shared__ bf16_t As[128][64];
  __shared__ bf16_t Bs[128][64];

  const int tid  = threadIdx.x;
  const int w    = tid >> 6;
  const int lane = tid & 63;
  const int wm   = (w & 1) * 64;
  const int wd   = (w >> 1) * 64;
  const int lrow = lane & 15;
  const int lk   = (lane >> 4) * 8;

  const int sub  = lane >> 3;        // 0..7 (row within 8-row stripe)
  const int scol = (lane & 7) * 8;   // 0..56 (elem col)

  f32x4 acc[4][4] = {};

  const int kbeg = kc * KCHUNK;
  for (int k0 = kbeg; k0 < kbeg + KCHUNK; k0 += 64) {
    __syncthreads();   // prior iter's ds_reads done before overwrite
#pragma unroll
    for (int c = 0; c < 4; ++c) {
      const int rr = (w * 4 + c) * 8 + sub;   // row 0..127
      GLDS(q + (size_t)(tile_m + rr) * N_ + k0 + scol,
           &As[0][0] + (w * 4 + c) * 512);
      GLDS(k + (size_t)(tile_d + rr) * N_ + k0 + scol,
           &Bs[0][0] + (w * 4 + c) * 512);
    }
    __syncthreads();   // drains vmcnt: staged data visible
#pragma unroll
    for (int kk = 0; kk < 64; kk += 32) {
      bf16x8 af[4], bfr[4];
#pragma unroll
      for (int i = 0; i < 4; ++i)
        af[i] = *(const bf16x8*)(&As[wm + i * 16 + lrow][kk + lk]);
#pragma unroll
      for (int j = 0; j < 4; ++j)
        bfr[j] = *(const bf16x8*)(&Bs[wd + j * 16 + lrow][kk + lk]);
#pragma unroll
      for (int i = 0; i < 4; ++i)
#pragma unroll
        for (int j = 0; j < 4; ++j)
          acc[i][j] = MFMA(af[i], bfr[j], acc[i][j]);
    }
  }

  // C/D layout: col = lane&15, row = (lane>>4)*4 + r
  float* Eb = g_Ep + (((size_t)kc * 3 + s) * B_ + b) * (size_t)C_ * C_;
  const int orow0 = tile_m + wm + (lane >> 4) * 4;
  const int ocol0 = tile_d + wd + (lane & 15);
#pragma unroll
  for (int i = 0; i < 4; ++i)
#pragma unroll
    for (int j = 0; j < 4; ++j)
#pragma unroll
      for (int r = 0; r < 4; ++r)
        Eb[(size_t)(orow0 + i * 16 + r) * C_ + (ocol0 + j * 16)] = acc[i][j][r];
}

// ---------------------------------------------------------------------------
// Kernel 2: attnT[b][d][c] = sum_s exp(min_d E_s - E_s[c,d]) / Z_s   (bf16)
// One wave per c-row (4 rows/block), shuffle reductions, sums KSPLIT partials.
// grid (C/4, B).
// ---------------------------------------------------------------------------
__global__ __launch_bounds__(256) void softmax_kernel()
{
  const int b    = blockIdx.y;
  const int c    = blockIdx.x * 4 + (threadIdx.x >> 6);
  const int lane = threadIdx.x & 63;
  const int d0   = lane * 4;

  float a0 = 0.f, a1 = 0.f, a2 = 0.f, a3 = 0.f;
#pragma unroll
  for (int s = 0; s < 3; ++s) {
    float e0 = 0.f, e1 = 0.f, e2 = 0.f, e3 = 0.f;
#pragma unroll
    for (int kc = 0; kc < KSPLIT; ++kc) {
      const float4 ep = *(const float4*)(
          g_Ep + ((((size_t)kc * 3 + s) * B_ + b) * C_ + c) * (size_t)C_ + d0);
      e0 += ep.x; e1 += ep.y; e2 += ep.z; e3 += ep.w;
    }
    float mn = fminf(fminf(e0, e1), fminf(e2, e3));
#pragma unroll
    for (int m = 32; m > 0; m >>= 1) mn = fminf(mn, __shfl_xor(mn, m));
    const float p0 = __expf(mn - e0);   // <= 1; min term gives exactly 1
    const float p1 = __expf(mn - e1);
    const float p2 = __expf(mn - e2);
    const float p3 = __expf(mn - e3);
    float Z = p0 + p1 + p2 + p3;
#pragma unroll
    for (int m = 32; m > 0; m >>= 1) Z += __shfl_xor(Z, m);
    const float rZ = 1.0f / Z;
    a0 += p0 * rZ; a1 += p1 * rZ; a2 += p2 * rZ; a3 += p3 * rZ;
  }
  bf16_t* At = g_attnT + (size_t)b * C_ * C_;   // [d][c], transposed for kernel 3
  At[(size_t)(d0 + 0) * C_ + c] = (bf16_t)a0;
  At[(size_t)(d0 + 1) * C_ + c] = (bf16_t)a1;
  At[(size_t)(d0 + 2) * C_ + c] = (bf16_t)a2;
  At[(size_t)(d0 + 3) * C_ + c] = (bf16_t)a3;
}

// ---------------------------------------------------------------------------
// Kernel 3: M[b][o][d] = sum_c conv_w[o,c] * attnT[b][d][c]   (bf16 out)
// ---------------------------------------------------------------------------
__global__ __launch_bounds__(256) void mconv_kernel()
{
  const int tile = blockIdx.x;  // 0..3
  const int b    = blockIdx.y;
  const int tile_o = (tile & 1) * 128;
  const int tile_d = (tile >> 1) * 128;
  const int tid  = threadIdx.x;
  const int w    = tid >> 6;
  const int lane = tid & 63;
  const int wo   = (w & 1) * 64;
  const int wd   = (w >> 1) * 64;
  const int lrow = lane & 15;
  const int lk   = (lane >> 4) * 8;

  const bf16_t* At = g_attnT + (size_t)b * C_ * C_;
  f32x4 acc[4][4] = {};

  for (int c0 = 0; c0 < C_; c0 += 32) {
    bf16x8 af[4], bfr[4];
#pragma unroll
    for (int i = 0; i < 4; ++i)
      af[i] = *(const bf16x8*)(g_cw + (size_t)(tile_o + wo + i * 16 + lrow) * C_ + c0 + lk);
#pragma unroll
    for (int j = 0; j < 4; ++j)
      bfr[j] = *(const bf16x8*)(At + (size_t)(tile_d + wd + j * 16 + lrow) * C_ + c0 + lk);
#pragma unroll
    for (int i = 0; i < 4; ++i)
#pragma unroll
      for (int j = 0; j < 4; ++j)
        acc[i][j] = MFMA(af[i], bfr[j], acc[i][j]);
  }

  bf16_t* Mb = g_M + (size_t)b * C_ * C_;
  const int orow0 = tile_o + wo + (lane >> 4) * 4;
  const int ocol0 = tile_d + wd + (lane & 15);
#pragma unroll
  for (int i = 0; i < 4; ++i)
#pragma unroll
    for (int j = 0; j < 4; ++j)
#pragma unroll
      for (int r = 0; r < 4; ++r)
        Mb[(size_t)(orow0 + i * 16 + r) * C_ + (ocol0 + j * 16)] = (bf16_t)acc[i][j][r];
}

// ---------------------------------------------------------------------------
// Kernel 4a: P[b][o][n] = sum_d M[b,o,d] * Q[b,d,n]   (bf16 out)
// Same direct-to-LDS NT structure as energy_kernel: A rows = M[o][d],
// B rows = qT[n][d], BK=64, 4 K-steps. grid (N/128, 2, B).
// ---------------------------------------------------------------------------
__global__ __launch_bounds__(256) void pmq_kernel()
{
  const int tile_n = blockIdx.x * 128;          // 0..31
  const int tile_o = blockIdx.y * 128;          // 0..1
  const int b      = blockIdx.z;

  const bf16_t* Mb = g_M  + (size_t)b * C_ * C_;
  const bf16_t* Qt = g_qT + (size_t)b * N_ * C_;

  __shared__ bf16_t As[128][64];  // M rows   [o][d]
  __shared__ bf16_t Bs[128][64];  // qT rows  [n][d]

  const int tid  = threadIdx.x;
  const int w    = tid >> 6;
  const int lane = tid & 63;
  const int wo   = (w & 1) * 64;
  const int wn   = (w >> 1) * 64;
  const int lrow = lane & 15;
  const int lk   = (lane >> 4) * 8;

  const int sub  = lane >> 3;        // 0..7
  const int scol = (lane & 7) * 8;   // 0..56

  f32x4 acc[4][4] = {};

  for (int d0 = 0; d0 < C_; d0 += 64) {
    __syncthreads();
#pragma unroll
    for (int c = 0; c < 4; ++c) {
      const int rr = (w * 4 + c) * 8 + sub;
      GLDS(Mb + (size_t)(tile_o + rr) * C_ + d0 + scol,
           &As[0][0] + (w * 4 + c) * 512);
      GLDS(Qt + (size_t)(tile_n + rr) * C_ + d0 + scol,
           &Bs[0][0] + (w * 4 + c) * 512);
    }
    __syncthreads();
#pragma unroll
    for (int kk = 0; kk < 64; kk += 32) {
      bf16x8 af[4], bfr[4];
#pragma unroll
      for (int i = 0; i < 4; ++i)
        af[i] = *(const bf16x8*)(&As[wo + i * 16 + lrow][kk + lk]);
#pragma unroll
      for (int j = 0; j < 4; ++j)
        bfr[j] = *(const bf16x8*)(&Bs[wn + j * 16 + lrow][kk + lk]);
#pragma unroll
      for (int i = 0; i < 4; ++i)
#pragma unroll
        for (int j = 0; j < 4; ++j)
          acc[i][j] = MFMA(af[i], bfr[j], acc[i][j]);
    }
  }

  // C/D layout: col = lane&15 (n), row = (lane>>4)*4 + r (o)
  bf16_t* Pb = g_P + (size_t)b * C_ * N_;
  const int orow0 = tile_o + wo + (lane >> 4) * 4;
  const int ocol0 = tile_n + wn + (lane & 15);
#pragma unroll
  for (int i = 0; i < 4; ++i)
#pragma unroll
    for (int j = 0; j < 4; ++j)
#pragma unroll
      for (int r = 0; r < 4; ++r)
        Pb[(size_t)(orow0 + i * 16 + r) * N_ + (ocol0 + j * 16)] = (bf16_t)acc[i][j][r];
}

// ---------------------------------------------------------------------------
// Kernel 4b: out[b][o][n] = gamma*(P[b,o,n] + bias[o]) + x[b,o,n]
// Pure streaming; one block per (b,o) row; 16 elems/thread, vector I/O.
// grid (B*C).
// ---------------------------------------------------------------------------
__global__ __launch_bounds__(256) void epilogue_kernel(
    const void* __restrict__ xraw, void* __restrict__ outraw)
{
  const int row  = blockIdx.x;            // b*C_ + o
  const int o    = row & (C_ - 1);
  const size_t roff = (size_t)row * N_ + (size_t)threadIdx.x * 16;

  const float g    = g_gamma;
  const float bias = g_cb[o];

  const bf16x8 p0 = *(const bf16x8*)(g_P + roff);
  const bf16x8 p1 = *(const bf16x8*)(g_P + roff + 8);
  float v[16];
#pragma unroll
  for (int k = 0; k < 8; ++k) {
    v[k]     = g * ((float)p0[k] + bias);
    v[8 + k] = g * ((float)p1[k] + bias);
  }

  if (g_mode == MODE_F32) {
    const float* xp = (const float*)xraw + roff;
    float*       op = (float*)outraw + roff;
#pragma unroll
    for (int q4 = 0; q4 < 4; ++q4) {
      float4 xv = *(const float4*)(xp + q4 * 4);
      float4 ov;
      ov.x = v[q4 * 4 + 0] + xv.x;
      ov.y = v[q4 * 4 + 1] + xv.y;
      ov.z = v[q4 * 4 + 2] + xv.z;
      ov.w = v[q4 * 4 + 3] + xv.w;
      *(float4*)(op + q4 * 4) = ov;
    }
  } else {
    const bf16_t* xp = (const bf16_t*)xraw + roff;
    bf16_t*       op = (bf16_t*)outraw + roff;
#pragma unroll
    for (int p = 0; p < 2; ++p) {
      bf16x8 xv = *(const bf16x8*)(xp + p * 8);
      bf16x8 ov;
#pragma unroll
      for (int k = 0; k < 8; ++k)
        ov[k] = (bf16_t)(v[p * 8 + k] + (float)xv[k]);
      *(bf16x8*)(op + p * 8) = ov;
    }
  }
}

// ---------------------------------------------------------------------------
extern "C" void kernel_launch(void* const* d_in, const int* in_sizes, int n_in,
                              void* d_out, int out_size, void* d_ws, size_t ws_size,
                              hipStream_t stream)
{
  const void* x  = d_in[0];
  const void* y  = d_in[1];
  const void* z  = d_in[2];
  const void* cw = d_in[3];
  const void* cb = d_in[4];
  const void* gm = d_in[5];
  (void)d_ws; (void)ws_size;

  detect_kernel   <<<1,                       256, 0, stream>>>((const float*)x);
  convert_big     <<<dim3(8192, 2),           256, 0, stream>>>(y, z);
  convert_params  <<<1,                       256, 0, stream>>>(cw, cb, gm);
  convert_xT      <<<dim3(N_ / 64, C_ / 64, B_), 256, 0, stream>>>(x);
  energy_kernel   <<<dim3(4 * KSPLIT, 3, B_), 256, 0, stream>>>();
  softmax_kernel  <<<dim3(C_ / 4, B_),        256, 0, stream>>>();
  mconv_kernel    <<<dim3(4, B_),             256, 0, stream>>>();
  pmq_kernel      <<<dim3(N_ / 128, 2, B_),   256, 0, stream>>>();
  epilogue_kernel <<<dim3(B_ * C_),           256, 0, stream>>>(x, d_out);
}

// Round 4
// 381.268 us; speedup vs baseline: 1.0813x; 1.0813x over previous
//
#include <hip/hip_runtime.h>
#include <hip/hip_bf16.h>

// Problem: B=16, C=256, H=W=64 -> N=4096.
// ref: attn = sum_s softmax(max-E_s) over last dim, E_s = Q K_s^T (reduce over N)
//      out  = gamma * (conv_w @ (attn @ Q) + bias) + x
// fused as: M = conv_w @ attn  (tiny GEMM), P = M @ Q, out = gamma*(P+bias)+x
//
// v5 changes vs v4 (412 us) / v3 (406 us):
//  - convert_big REMOVED (~670 MB = ~110 us of pure streaming overhead).
//    energy_kernel now reads raw y/z directly with in-register fp32->bf16
//    conversion during staging (bitwise-identical rounding to the old pass).
//  - energy tile widened to 256(c-full) x 128(d), 512 thr / 8 waves, so each
//    K-element is read EXACTLY ONCE from HBM (was 2x via tile_m split).
//    KSPLIT=4 -> grid (8,3,16)=384 blocks. Kernel becomes HBM-bound.
//  - pmq reverted to v3 reg-staged padded-LDS form (v4's global_load_lds
//    regressed energy: conflicts 3.1M->9.4M, no MfmaUtil gain).

#define B_ 16
#define C_ 256
#define N_ 4096
#define KSPLIT 4
#define KCHUNK (N_ / KSPLIT)   // 1024

#define MODE_BF16 0
#define MODE_F32  1

typedef __bf16 bf16_t;
typedef bf16_t bf16x8 __attribute__((ext_vector_type(8)));
typedef float  f32x4  __attribute__((ext_vector_type(4)));

#define MFMA(a, b, c) __builtin_amdgcn_mfma_f32_16x16x32_bf16(a, b, c, 0, 0, 0)

// Scratch (module-load allocated; no ws_size dependence; graph-safe).
__device__ int    g_mode;
__device__ bf16_t g_q[(size_t)B_ * C_ * N_];       // canonical x (33.5 MB)
__device__ bf16_t g_qT[(size_t)B_ * N_ * C_];      // x transposed [b][n][c] (33.5 MB)
__device__ bf16_t g_cw[C_ * C_];
__device__ float  g_cb[C_];
__device__ float  g_gamma;
__device__ float  g_Ep[(size_t)KSPLIT * 3 * B_ * C_ * C_];  // partial E, 50.3 MB
__device__ bf16_t g_attnT[(size_t)B_ * C_ * C_];
__device__ bf16_t g_M[(size_t)B_ * C_ * C_];
__device__ bf16_t g_P[(size_t)B_ * C_ * N_];       // P = M @ Q (33.5 MB)

// ---------------------------------------------------------------------------
// Kernel 0: dtype sniff. fp32 N(0,1) data -> abs bits <= ~0x40C00000.
// bf16 pairs misread as fp32 -> exponent field from bf16 payload bits,
// values ~1e37 almost surely. Threshold 1024.0f separates cleanly.
// ---------------------------------------------------------------------------
__global__ __launch_bounds__(256) void detect_kernel(const float* __restrict__ xf)
{
  __shared__ unsigned red[256];
  const int t = threadIdx.x;
  unsigned m = 0;
  for (int i = t; i < 4096; i += 256)
    m = max(m, __float_as_uint(xf[i]) & 0x7fffffffu);
  red[t] = m;
  __syncthreads();
  for (int s = 128; s > 0; s >>= 1) {
    if (t < s) red[t] = max(red[t], red[t + s]);
    __syncthreads();
  }
  if (t == 0) g_mode = (red[0] > 0x44800000u) ? MODE_BF16 : MODE_F32;
}

// ---------------------------------------------------------------------------
// Kernel 0d: canonicalize x into bf16 AND materialize x^T [b][n][c] in bf16.
// 64x64 tiles via LDS. grid (N/64, C/64, B).
// ---------------------------------------------------------------------------
__global__ __launch_bounds__(256) void convert_xT(const void* __restrict__ x)
{
  __shared__ bf16_t Ts[64][72];   // [c_local][n_local], padded
  const int t  = threadIdx.x;
  const int r  = t >> 3;          // 0..31
  const int co = (t & 7) * 8;     // 0..56
  const int n0 = blockIdx.x * 64;
  const int c0 = blockIdx.y * 64;
  const int b  = blockIdx.z;
  const size_t base = (size_t)b * C_ * N_;

  bf16x8 v[2];
  if (g_mode == MODE_F32) {
#pragma unroll
    for (int p = 0; p < 2; ++p) {
      const float* s = (const float*)x + base + (size_t)(c0 + r + p * 32) * N_ + n0 + co;
      float4 a = *(const float4*)s;
      float4 b4 = *(const float4*)(s + 4);
      bf16x8 w;
      w[0] = (bf16_t)a.x; w[1] = (bf16_t)a.y; w[2] = (bf16_t)a.z; w[3] = (bf16_t)a.w;
      w[4] = (bf16_t)b4.x; w[5] = (bf16_t)b4.y; w[6] = (bf16_t)b4.z; w[7] = (bf16_t)b4.w;
      v[p] = w;
    }
  } else {
#pragma unroll
    for (int p = 0; p < 2; ++p)
      v[p] = *(const bf16x8*)((const bf16_t*)x + base + (size_t)(c0 + r + p * 32) * N_ + n0 + co);
  }

  // write-through normal bf16 staging + stage tile in LDS
#pragma unroll
  for (int p = 0; p < 2; ++p) {
    *(bf16x8*)(g_q + base + (size_t)(c0 + r + p * 32) * N_ + n0 + co) = v[p];
    *(bf16x8*)(&Ts[r + p * 32][co]) = v[p];
  }
  __syncthreads();

  // write transposed rows: QT[b][n0+n][c0+co .. +7]
#pragma unroll
  for (int p = 0; p < 2; ++p) {
    const int n = r + p * 32;
    bf16x8 w;
#pragma unroll
    for (int j = 0; j < 8; ++j) w[j] = Ts[co + j][n];
    *(bf16x8*)(g_qT + (size_t)b * N_ * C_ + (size_t)(n0 + n) * C_ + c0 + co) = w;
  }
}

// ---------------------------------------------------------------------------
// Kernel 0c: canonicalize conv_w (bf16), conv_b + gamma (fp32). 1 block.
// ---------------------------------------------------------------------------
__global__ __launch_bounds__(256) void convert_params(
    const void* __restrict__ cw, const void* __restrict__ cb,
    const void* __restrict__ gm)
{
  const int t = threadIdx.x;
  if (g_mode == MODE_F32) {
    for (int i = t * 8; i < C_ * C_; i += 256 * 8) {
      const float* s = (const float*)cw + i;
      float4 a = *(const float4*)s;
      float4 b = *(const float4*)(s + 4);
      bf16x8 v;
      v[0] = (bf16_t)a.x; v[1] = (bf16_t)a.y; v[2] = (bf16_t)a.z; v[3] = (bf16_t)a.w;
      v[4] = (bf16_t)b.x; v[5] = (bf16_t)b.y; v[6] = (bf16_t)b.z; v[7] = (bf16_t)b.w;
      *(bf16x8*)(g_cw + i) = v;
    }
    if (t < C_) g_cb[t] = ((const float*)cb)[t];
    if (t == 0) g_gamma = ((const float*)gm)[0];
  } else {
    for (int i = t * 8; i < C_ * C_; i += 256 * 8)
      *(bf16x8*)(g_cw + i) = *(const bf16x8*)((const bf16_t*)cw + i);
    if (t < C_) g_cb[t] = (float)((const bf16_t*)cb)[t];
    if (t == 0) g_gamma = (float)((const bf16_t*)gm)[0];
  }
}

// ---------------------------------------------------------------------------
// Kernel 1: Ep[kc][s][b][c][d] = sum_{n in chunk} Q[b,c,n] * Ksrc_s[b,d,n]
// Tile 256(c, full) x 128(d), 512 thr / 8 waves of 64x64, BK=64, reg-staged
// padded LDS. Each K-element read ONCE from HBM: s=0 from g_q (bf16),
// s in {1,2} from raw y/z with inline fp32->bf16 cvt (or bf16 passthrough).
// grid (2 dtile * KSPLIT, 3, B) = (8, 3, 16).
// ---------------------------------------------------------------------------
__global__ __launch_bounds__(512) void energy_kernel(
    const void* __restrict__ yraw, const void* __restrict__ zraw)
{
  const int dtile = blockIdx.x & 1;   // 0..1
  const int kc    = blockIdx.x >> 1;  // 0..3
  const int s     = blockIdx.y;       // 0..2
  const int b     = blockIdx.z;       // 0..15

  const bf16_t* q = g_q + (size_t)b * C_ * N_;   // A panel: all 256 c-rows
  const int tile_d = dtile * 128;

  __shared__ bf16_t As[256][72];  // stride 144 B: 16B-aligned, non-pow2 banks
  __shared__ bf16_t Bs[128][72];

  const int tid  = threadIdx.x;
  const int w    = tid >> 6;          // 0..7
  const int lane = tid & 63;
  const int wm   = (w & 3) * 64;      // c-offset of wave tile
  const int wd   = (w >> 2) * 64;     // d-offset of wave tile
  const int lrow = lane & 15;
  const int lk   = (lane >> 4) * 8;

  const int srow = tid >> 3;          // 0..63
  const int soff = (tid & 7) * 8;     // 0..56

  // B-panel source (wave-uniform selection)
  const int mode = g_mode;
  const bf16_t* kb16 = nullptr;
  const float*  kf32 = nullptr;
  if (s == 0) {
    kb16 = g_q + (size_t)b * C_ * N_;
  } else if (mode == MODE_BF16) {
    kb16 = (const bf16_t*)(s == 1 ? yraw : zraw) + (size_t)b * C_ * N_;
  } else {
    kf32 = (const float*)(s == 1 ? yraw : zraw) + (size_t)b * C_ * N_;
  }

  f32x4 acc[4][4] = {};

  const int kbeg = kc * KCHUNK;
  for (int k0 = kbeg; k0 < kbeg + KCHUNK; k0 += 64) {
    // --- load staging into registers (A: 4 rows/thread; B: 2 rows/thread) ---
    bf16x8 av[4], bv[2];
#pragma unroll
    for (int i = 0; i < 4; ++i)
      av[i] = *(const bf16x8*)(q + (size_t)(srow + i * 64) * N_ + k0 + soff);
    if (kf32) {
#pragma unroll
      for (int i = 0; i < 2; ++i) {
        const float* sp = kf32 + (size_t)(tile_d + srow + i * 64) * N_ + k0 + soff;
        float4 a = *(const float4*)sp;
        float4 c = *(const float4*)(sp + 4);
        bf16x8 v;
        v[0] = (bf16_t)a.x; v[1] = (bf16_t)a.y; v[2] = (bf16_t)a.z; v[3] = (bf16_t)a.w;
        v[4] = (bf16_t)c.x; v[5] = (bf16_t)c.y; v[6] = (bf16_t)c.z; v[7] = (bf16_t)c.w;
        bv[i] = v;
      }
    } else {
#pragma unroll
      for (int i = 0; i < 2; ++i)
        bv[i] = *(const bf16x8*)(kb16 + (size_t)(tile_d + srow + i * 64) * N_ + k0 + soff);
    }
    __syncthreads();   // prior iter's LDS reads complete before overwrite
#pragma unroll
    for (int i = 0; i < 4; ++i)
      *(bf16x8*)(&As[srow + i * 64][soff]) = av[i];
#pragma unroll
    for (int i = 0; i < 2; ++i)
      *(bf16x8*)(&Bs[srow + i * 64][soff]) = bv[i];
    __syncthreads();
    // --- MFMA phase ---
#pragma unroll
    for (int kk = 0; kk < 64; kk += 32) {
      bf16x8 af[4], bfr[4];
#pragma unroll
      for (int i = 0; i < 4; ++i)
        af[i] = *(const bf16x8*)(&As[wm + i * 16 + lrow][kk + lk]);
#pragma unroll
      for (int j = 0; j < 4; ++j)
        bfr[j] = *(const bf16x8*)(&Bs[wd + j * 16 + lrow][kk + lk]);
#pragma unroll
      for (int i = 0; i < 4; ++i)
#pragma unroll
        for (int j = 0; j < 4; ++j)
          acc[i][j] = MFMA(af[i], bfr[j], acc[i][j]);
    }
  }

  // C/D layout: col = lane&15, row = (lane>>4)*4 + r
  float* Eb = g_Ep + (((size_t)kc * 3 + s) * B_ + b) * (size_t)C_ * C_;
  const int orow0 = wm + (lane >> 4) * 4;
  const int ocol0 = tile_d + wd + (lane & 15);
#pragma unroll
  for (int i = 0; i < 4; ++i)
#pragma unroll
    for (int j = 0; j < 4; ++j)
#pragma unroll
      for (int r = 0; r < 4; ++r)
        Eb[(size_t)(orow0 + i * 16 + r) * C_ + (ocol0 + j * 16)] = acc[i][j][r];
}

// ---------------------------------------------------------------------------
// Kernel 2: attnT[b][d][c] = sum_s exp(min_d E_s - E_s[c,d]) / Z_s   (bf16)
// One wave per c-row (4 rows/block), shuffle reductions, sums KSPLIT partials.
// grid (C/4, B).
// ---------------------------------------------------------------------------
__global__ __launch_bounds__(256) void softmax_kernel()
{
  const int b    = blockIdx.y;
  const int c    = blockIdx.x * 4 + (threadIdx.x >> 6);
  const int lane = threadIdx.x & 63;
  const int d0   = lane * 4;

  float a0 = 0.f, a1 = 0.f, a2 = 0.f, a3 = 0.f;
#pragma unroll
  for (int s = 0; s < 3; ++s) {
    float e0 = 0.f, e1 = 0.f, e2 = 0.f, e3 = 0.f;
#pragma unroll
    for (int kc = 0; kc < KSPLIT; ++kc) {
      const float4 ep = *(const float4*)(
          g_Ep + ((((size_t)kc * 3 + s) * B_ + b) * C_ + c) * (size_t)C_ + d0);
      e0 += ep.x; e1 += ep.y; e2 += ep.z; e3 += ep.w;
    }
    float mn = fminf(fminf(e0, e1), fminf(e2, e3));
#pragma unroll
    for (int m = 32; m > 0; m >>= 1) mn = fminf(mn, __shfl_xor(mn, m));
    const float p0 = __expf(mn - e0);   // <= 1; min term gives exactly 1
    const float p1 = __expf(mn - e1);
    const float p2 = __expf(mn - e2);
    const float p3 = __expf(mn - e3);
    float Z = p0 + p1 + p2 + p3;
#pragma unroll
    for (int m = 32; m > 0; m >>= 1) Z += __shfl_xor(Z, m);
    const float rZ = 1.0f / Z;
    a0 += p0 * rZ; a1 += p1 * rZ; a2 += p2 * rZ; a3 += p3 * rZ;
  }
  bf16_t* At = g_attnT + (size_t)b * C_ * C_;   // [d][c], transposed for kernel 3
  At[(size_t)(d0 + 0) * C_ + c] = (bf16_t)a0;
  At[(size_t)(d0 + 1) * C_ + c] = (bf16_t)a1;
  At[(size_t)(d0 + 2) * C_ + c] = (bf16_t)a2;
  At[(size_t)(d0 + 3) * C_ + c] = (bf16_t)a3;
}

// ---------------------------------------------------------------------------
// Kernel 3: M[b][o][d] = sum_c conv_w[o,c] * attnT[b][d][c]   (bf16 out)
// ---------------------------------------------------------------------------
__global__ __launch_bounds__(256) void mconv_kernel()
{
  const int tile = blockIdx.x;  // 0..3
  const int b    = blockIdx.y;
  const int tile_o = (tile & 1) * 128;
  const int tile_d = (tile >> 1) * 128;
  const int tid  = threadIdx.x;
  const int w    = tid >> 6;
  const int lane = tid & 63;
  const int wo   = (w & 1) * 64;
  const int wd   = (w >> 1) * 64;
  const int lrow = lane & 15;
  const int lk   = (lane >> 4) * 8;

  const bf16_t* At = g_attnT + (size_t)b * C_ * C_;
  f32x4 acc[4][4] = {};

  for (int c0 = 0; c0 < C_; c0 += 32) {
    bf16x8 af[4], bfr[4];
#pragma unroll
    for (int i = 0; i < 4; ++i)
      af[i] = *(const bf16x8*)(g_cw + (size_t)(tile_o + wo + i * 16 + lrow) * C_ + c0 + lk);
#pragma unroll
    for (int j = 0; j < 4; ++j)
      bfr[j] = *(const bf16x8*)(At + (size_t)(tile_d + wd + j * 16 + lrow) * C_ + c0 + lk);
#pragma unroll
    for (int i = 0; i < 4; ++i)
#pragma unroll
      for (int j = 0; j < 4; ++j)
        acc[i][j] = MFMA(af[i], bfr[j], acc[i][j]);
  }

  bf16_t* Mb = g_M + (size_t)b * C_ * C_;
  const int orow0 = tile_o + wo + (lane >> 4) * 4;
  const int ocol0 = tile_d + wd + (lane & 15);
#pragma unroll
  for (int i = 0; i < 4; ++i)
#pragma unroll
    for (int j = 0; j < 4; ++j)
#pragma unroll
      for (int r = 0; r < 4; ++r)
        Mb[(size_t)(orow0 + i * 16 + r) * C_ + (ocol0 + j * 16)] = (bf16_t)acc[i][j][r];
}

// ---------------------------------------------------------------------------
// Kernel 4a: P[b][o][n] = sum_d M[b,o,d] * Q[b,d,n]   (bf16 out)
// v3 reg-staged NT structure: A rows = M[o][d], B rows = qT[n][d], BK=64.
// grid (N/128, 2, B).
// ---------------------------------------------------------------------------
__global__ __launch_bounds__(256) void pmq_kernel()
{
  const int tile_n = blockIdx.x * 128;          // 0..31
  const int tile_o = blockIdx.y * 128;          // 0..1
  const int b      = blockIdx.z;

  const bf16_t* Mb = g_M  + (size_t)b * C_ * C_;
  const bf16_t* Qt = g_qT + (size_t)b * N_ * C_;

  __shared__ bf16_t As[128][72];  // M rows   [o][d]
  __shared__ bf16_t Bs[128][72];  // qT rows  [n][d]

  const int tid  = threadIdx.x;
  const int w    = tid >> 6;
  const int lane = tid & 63;
  const int wo   = (w & 1) * 64;
  const int wn   = (w >> 1) * 64;
  const int lrow = lane & 15;
  const int lk   = (lane >> 4) * 8;

  const int srow = tid >> 3;        // 0..31
  const int soff = (tid & 7) * 8;   // 0..56

  f32x4 acc[4][4] = {};

  for (int d0 = 0; d0 < C_; d0 += 64) {
    bf16x8 av[4], bv[4];
#pragma unroll
    for (int i = 0; i < 4; ++i) {
      int r = srow + i * 32;
      av[i] = *(const bf16x8*)(Mb + (size_t)(tile_o + r) * C_ + d0 + soff);
      bv[i] = *(const bf16x8*)(Qt + (size_t)(tile_n + r) * C_ + d0 + soff);
    }
    __syncthreads();
#pragma unroll
    for (int i = 0; i < 4; ++i) {
      int r = srow + i * 32;
      *(bf16x8*)(&As[r][soff]) = av[i];
      *(bf16x8*)(&Bs[r][soff]) = bv[i];
    }
    __syncthreads();
#pragma unroll
    for (int kk = 0; kk < 64; kk += 32) {
      bf16x8 af[4], bfr[4];
#pragma unroll
      for (int i = 0; i < 4; ++i)
        af[i] = *(const bf16x8*)(&As[wo + i * 16 + lrow][kk + lk]);
#pragma unroll
      for (int j = 0; j < 4; ++j)
        bfr[j] = *(const bf16x8*)(&Bs[wn + j * 16 + lrow][kk + lk]);
#pragma unroll
      for (int i = 0; i < 4; ++i)
#pragma unroll
        for (int j = 0; j < 4; ++j)
          acc[i][j] = MFMA(af[i], bfr[j], acc[i][j]);
    }
  }

  // C/D layout: col = lane&15 (n), row = (lane>>4)*4 + r (o)
  bf16_t* Pb = g_P + (size_t)b * C_ * N_;
  const int orow0 = tile_o + wo + (lane >> 4) * 4;
  const int ocol0 = tile_n + wn + (lane & 15);
#pragma unroll
  for (int i = 0; i < 4; ++i)
#pragma unroll
    for (int j = 0; j < 4; ++j)
#pragma unroll
      for (int r = 0; r < 4; ++r)
        Pb[(size_t)(orow0 + i * 16 + r) * N_ + (ocol0 + j * 16)] = (bf16_t)acc[i][j][r];
}

// ---------------------------------------------------------------------------
// Kernel 4b: out[b][o][n] = gamma*(P[b,o,n] + bias[o]) + x[b,o,n]
// Pure streaming; one block per (b,o) row; 16 elems/thread, vector I/O.
// grid (B*C).
// ---------------------------------------------------------------------------
__global__ __launch_bounds__(256) void epilogue_kernel(
    const void* __restrict__ xraw, void* __restrict__ outraw)
{
  const int row  = blockIdx.x;            // b*C_ + o
  const int o    = row & (C_ - 1);
  const size_t roff = (size_t)row * N_ + (size_t)threadIdx.x * 16;

  const float g    = g_gamma;
  const float bias = g_cb[o];

  const bf16x8 p0 = *(const bf16x8*)(g_P + roff);
  const bf16x8 p1 = *(const bf16x8*)(g_P + roff + 8);
  float v[16];
#pragma unroll
  for (int k = 0; k < 8; ++k) {
    v[k]     = g * ((float)p0[k] + bias);
    v[8 + k] = g * ((float)p1[k] + bias);
  }

  if (g_mode == MODE_F32) {
    const float* xp = (const float*)xraw + roff;
    float*       op = (float*)outraw + roff;
#pragma unroll
    for (int q4 = 0; q4 < 4; ++q4) {
      float4 xv = *(const float4*)(xp + q4 * 4);
      float4 ov;
      ov.x = v[q4 * 4 + 0] + xv.x;
      ov.y = v[q4 * 4 + 1] + xv.y;
      ov.z = v[q4 * 4 + 2] + xv.z;
      ov.w = v[q4 * 4 + 3] + xv.w;
      *(float4*)(op + q4 * 4) = ov;
    }
  } else {
    const bf16_t* xp = (const bf16_t*)xraw + roff;
    bf16_t*       op = (bf16_t*)outraw + roff;
#pragma unroll
    for (int p = 0; p < 2; ++p) {
      bf16x8 xv = *(const bf16x8*)(xp + p * 8);
      bf16x8 ov;
#pragma unroll
      for (int k = 0; k < 8; ++k)
        ov[k] = (bf16_t)(v[p * 8 + k] + (float)xv[k]);
      *(bf16x8*)(op + p * 8) = ov;
    }
  }
}

// ---------------------------------------------------------------------------
extern "C" void kernel_launch(void* const* d_in, const int* in_sizes, int n_in,
                              void* d_out, int out_size, void* d_ws, size_t ws_size,
                              hipStream_t stream)
{
  const void* x  = d_in[0];
  const void* y  = d_in[1];
  const void* z  = d_in[2];
  const void* cw = d_in[3];
  const void* cb = d_in[4];
  const void* gm = d_in[5];
  (void)d_ws; (void)ws_size;

  detect_kernel   <<<1,                       256, 0, stream>>>((const float*)x);
  convert_params  <<<1,                       256, 0, stream>>>(cw, cb, gm);
  convert_xT      <<<dim3(N_ / 64, C_ / 64, B_), 256, 0, stream>>>(x);
  energy_kernel   <<<dim3(2 * KSPLIT, 3, B_), 512, 0, stream>>>(y, z);
  softmax_kernel  <<<dim3(C_ / 4, B_),        256, 0, stream>>>();
  mconv_kernel    <<<dim3(4, B_),             256, 0, stream>>>();
  pmq_kernel      <<<dim3(N_ / 128, 2, B_),   256, 0, stream>>>();
  epilogue_kernel <<<dim3(B_ * C_),           256, 0, stream>>>(x, d_out);
}

// Round 5
// 374.206 us; speedup vs baseline: 1.1017x; 1.0189x over previous
//
#include <hip/hip_runtime.h>
#include <hip/hip_bf16.h>

// Problem: B=16, C=256, H=W=64 -> N=4096.
// ref: attn = sum_s softmax(max-E_s) over last dim, E_s = Q K_s^T (reduce over N)
//      out  = gamma * (conv_w @ (attn @ Q) + bias) + x
// fused as: M = conv_w @ attn  (tiny GEMM), P = M @ Q, out = gamma*(P+bias)+x
//
// v6 changes vs v5 (381 us):
//  - energy reverted to the proven v3 geometry (128x128 tiles, grid 768,
//    37 KB LDS, was 77.8 us) -- v5's 256x128 tile (55 KB LDS, grid 384)
//    starved the CUs (1.5 blocks/CU avg) and regressed to 94.9 us.
//    Kept: no convert_big (y/z read raw with inline cvt; x read directly
//    as bf16 when mode==BF16 -- counters prove bench mode IS bf16:
//    FETCH 130 MB << 536 MB unique fp32 y/z).
//  - convert_xT: transposed LDS read was 8-way bank-conflicted x16 scalar
//    reads/thread (pad stride 36 dw == 4j mod 32: column idx contributes 0).
//    Replaced pad with XOR n-block swizzle (nblk ^= (c>>3)&7): both store
//    and transposed read now conflict-free. g_q write skipped in BF16 mode.
//  - mconv re-tiled 128x128 -> 64x64 (grid 64 -> 256 blocks = 1/CU).
//  - detect+params merged into setup_kernel (one launch fewer).

#define B_ 16
#define C_ 256
#define N_ 4096
#define KSPLIT 4
#define KCHUNK (N_ / KSPLIT)   // 1024

#define MODE_BF16 0
#define MODE_F32  1

typedef __bf16 bf16_t;
typedef bf16_t bf16x8 __attribute__((ext_vector_type(8)));
typedef float  f32x4  __attribute__((ext_vector_type(4)));

#define MFMA(a, b, c) __builtin_amdgcn_mfma_f32_16x16x32_bf16(a, b, c, 0, 0, 0)

// Scratch (module-load allocated; no ws_size dependence; graph-safe).
__device__ int    g_mode;
__device__ bf16_t g_q[(size_t)B_ * C_ * N_];       // canonical x (F32 mode only)
__device__ bf16_t g_qT[(size_t)B_ * N_ * C_];      // x^T [b][n][c] (33.5 MB)
__device__ bf16_t g_cw[C_ * C_];
__device__ float  g_cb[C_];
__device__ float  g_gamma;
__device__ float  g_Ep[(size_t)KSPLIT * 3 * B_ * C_ * C_];  // partial E, 50.3 MB
__device__ bf16_t g_attnT[(size_t)B_ * C_ * C_];
__device__ bf16_t g_M[(size_t)B_ * C_ * C_];
__device__ bf16_t g_P[(size_t)B_ * C_ * N_];       // P = M @ Q (33.5 MB)

// ---------------------------------------------------------------------------
// Kernel 0: dtype sniff + param canonicalization, one block.
// fp32 N(0,1) -> abs bits <= ~0x40C00000; bf16 pair misread as fp32 ~1e37.
// ---------------------------------------------------------------------------
__global__ __launch_bounds__(256) void setup_kernel(
    const float* __restrict__ xf, const void* __restrict__ cw,
    const void* __restrict__ cb, const void* __restrict__ gm)
{
  __shared__ unsigned red[256];
  const int t = threadIdx.x;
  unsigned m = 0;
  for (int i = t; i < 4096; i += 256)
    m = max(m, __float_as_uint(xf[i]) & 0x7fffffffu);
  red[t] = m;
  __syncthreads();
  for (int s = 128; s > 0; s >>= 1) {
    if (t < s) red[t] = max(red[t], red[t + s]);
    __syncthreads();
  }
  const int mode = (red[0] > 0x44800000u) ? MODE_BF16 : MODE_F32;
  if (t == 0) g_mode = mode;

  if (mode == MODE_F32) {
    for (int i = t * 8; i < C_ * C_; i += 256 * 8) {
      const float* s = (const float*)cw + i;
      float4 a = *(const float4*)s;
      float4 b = *(const float4*)(s + 4);
      bf16x8 v;
      v[0] = (bf16_t)a.x; v[1] = (bf16_t)a.y; v[2] = (bf16_t)a.z; v[3] = (bf16_t)a.w;
      v[4] = (bf16_t)b.x; v[5] = (bf16_t)b.y; v[6] = (bf16_t)b.z; v[7] = (bf16_t)b.w;
      *(bf16x8*)(g_cw + i) = v;
    }
    if (t < C_) g_cb[t] = ((const float*)cb)[t];
    if (t == 0) g_gamma = ((const float*)gm)[0];
  } else {
    for (int i = t * 8; i < C_ * C_; i += 256 * 8)
      *(bf16x8*)(g_cw + i) = *(const bf16x8*)((const bf16_t*)cw + i);
    if (t < C_) g_cb[t] = (float)((const bf16_t*)cb)[t];
    if (t == 0) g_gamma = (float)((const bf16_t*)gm)[0];
  }
}

// ---------------------------------------------------------------------------
// Kernel 0d: materialize x^T [b][n][c] bf16 (and g_q bf16 copy in F32 mode).
// 64x64 tiles via XOR-swizzled LDS; both store and transposed read are
// bank-conflict-free (store banks (nblk^4p)*4+[0..3]; read banks
// (4p^k)*4 + r/2 cover all 32). grid (N/64, C/64, B).
// ---------------------------------------------------------------------------
__global__ __launch_bounds__(256) void convert_xT(const void* __restrict__ x)
{
  __shared__ bf16_t Ts[64][64];   // [c_local][n_swizzled], 8 KB
  const int t  = threadIdx.x;
  const int r  = t >> 3;          // 0..31
  const int nb = t & 7;           // n-block / c-block index
  const int co = nb * 8;
  const int n0 = blockIdx.x * 64;
  const int c0 = blockIdx.y * 64;
  const int b  = blockIdx.z;
  const size_t base = (size_t)b * C_ * N_;
  const int mode = g_mode;

  bf16x8 v[2];
  if (mode == MODE_F32) {
#pragma unroll
    for (int p = 0; p < 2; ++p) {
      const float* s = (const float*)x + base + (size_t)(c0 + r + p * 32) * N_ + n0 + co;
      float4 a = *(const float4*)s;
      float4 b4 = *(const float4*)(s + 4);
      bf16x8 w;
      w[0] = (bf16_t)a.x; w[1] = (bf16_t)a.y; w[2] = (bf16_t)a.z; w[3] = (bf16_t)a.w;
      w[4] = (bf16_t)b4.x; w[5] = (bf16_t)b4.y; w[6] = (bf16_t)b4.z; w[7] = (bf16_t)b4.w;
      v[p] = w;
    }
  } else {
#pragma unroll
    for (int p = 0; p < 2; ++p)
      v[p] = *(const bf16x8*)((const bf16_t*)x + base + (size_t)(c0 + r + p * 32) * N_ + n0 + co);
  }

#pragma unroll
  for (int p = 0; p < 2; ++p) {
    const int cl = r + p * 32;
    if (mode == MODE_F32)   // bf16 canonical copy needed only in F32 mode
      *(bf16x8*)(g_q + base + (size_t)(c0 + cl) * N_ + n0 + co) = v[p];
    const int swz = nb ^ ((cl >> 3) & 7);
    *(bf16x8*)(&Ts[cl][swz * 8]) = v[p];
  }
  __syncthreads();

  // transposed read: QT[b][n0+nl][c0+co .. +7]
#pragma unroll
  for (int p = 0; p < 2; ++p) {
    const int nl = r + p * 32;
    bf16x8 w;
#pragma unroll
    for (int j = 0; j < 8; ++j) {
      const int c = co + j;
      const int k = (c >> 3) & 7;   // == nb
      w[j] = Ts[c][(((nl >> 3) ^ k) * 8) + (nl & 7)];
    }
    *(bf16x8*)(g_qT + (size_t)b * N_ * C_ + (size_t)(n0 + nl) * C_ + c0 + co) = w;
  }
}

// ---------------------------------------------------------------------------
// Kernel 1: Ep[kc][s][b][c][d] = sum_{n in chunk} Q[b,c,n] * Ksrc_s[b,d,n]
// v3 geometry: 128x128 tile, 4 waves of 64x64, BK=64, reg-staged padded LDS,
// K split x4. grid (4 tiles * KSPLIT, 3, B) = (16,3,16)=768 blocks.
// A from x directly (BF16 mode) or g_q (F32); B from raw y/z w/ inline cvt.
// ---------------------------------------------------------------------------
__global__ __launch_bounds__(256) void energy_kernel(
    const void* __restrict__ xraw, const void* __restrict__ yraw,
    const void* __restrict__ zraw)
{
  const int tile = blockIdx.x & 3;   // 0..3
  const int kc   = blockIdx.x >> 2;  // 0..3
  const int s    = blockIdx.y;       // 0..2
  const int b    = blockIdx.z;       // 0..15

  const int mode = g_mode;
  const bf16_t* q =
      (mode == MODE_BF16 ? (const bf16_t*)xraw : g_q) + (size_t)b * C_ * N_;

  const bf16_t* kb16 = nullptr;
  const float*  kf32 = nullptr;
  if (s == 0) {
    kb16 = q;
  } else if (mode == MODE_BF16) {
    kb16 = (const bf16_t*)(s == 1 ? yraw : zraw) + (size_t)b * C_ * N_;
  } else {
    kf32 = (const float*)(s == 1 ? yraw : zraw) + (size_t)b * C_ * N_;
  }

  const int tile_m = (tile & 1) * 128;
  const int tile_d = (tile >> 1) * 128;

  __shared__ bf16_t As[128][72];  // stride 144 B: 16B-aligned rows, non-pow2
  __shared__ bf16_t Bs[128][72];

  const int tid  = threadIdx.x;
  const int w    = tid >> 6;
  const int lane = tid & 63;
  const int wm   = (w & 1) * 64;
  const int wd   = (w >> 1) * 64;
  const int lrow = lane & 15;
  const int lk   = (lane >> 4) * 8;

  const int srow = tid >> 3;        // 0..31
  const int soff = (tid & 7) * 8;   // 0..56

  f32x4 acc[4][4] = {};

  const int kbeg = kc * KCHUNK;
  for (int k0 = kbeg; k0 < kbeg + KCHUNK; k0 += 64) {
    bf16x8 av[4], bv[4];
#pragma unroll
    for (int i = 0; i < 4; ++i) {
      int r = srow + i * 32;
      av[i] = *(const bf16x8*)(q + (size_t)(tile_m + r) * N_ + k0 + soff);
    }
    if (kf32) {
#pragma unroll
      for (int i = 0; i < 4; ++i) {
        int r = srow + i * 32;
        const float* sp = kf32 + (size_t)(tile_d + r) * N_ + k0 + soff;
        float4 a = *(const float4*)sp;
        float4 c = *(const float4*)(sp + 4);
        bf16x8 v;
        v[0] = (bf16_t)a.x; v[1] = (bf16_t)a.y; v[2] = (bf16_t)a.z; v[3] = (bf16_t)a.w;
        v[4] = (bf16_t)c.x; v[5] = (bf16_t)c.y; v[6] = (bf16_t)c.z; v[7] = (bf16_t)c.w;
        bv[i] = v;
      }
    } else {
#pragma unroll
      for (int i = 0; i < 4; ++i) {
        int r = srow + i * 32;
        bv[i] = *(const bf16x8*)(kb16 + (size_t)(tile_d + r) * N_ + k0 + soff);
      }
    }
    __syncthreads();   // prior iter's LDS reads complete before overwrite
#pragma unroll
    for (int i = 0; i < 4; ++i) {
      int r = srow + i * 32;
      *(bf16x8*)(&As[r][soff]) = av[i];
      *(bf16x8*)(&Bs[r][soff]) = bv[i];
    }
    __syncthreads();
#pragma unroll
    for (int kk = 0; kk < 64; kk += 32) {
      bf16x8 af[4], bfr[4];
#pragma unroll
      for (int i = 0; i < 4; ++i)
        af[i] = *(const bf16x8*)(&As[wm + i * 16 + lrow][kk + lk]);
#pragma unroll
      for (int j = 0; j < 4; ++j)
        bfr[j] = *(const bf16x8*)(&Bs[wd + j * 16 + lrow][kk + lk]);
#pragma unroll
      for (int i = 0; i < 4; ++i)
#pragma unroll
        for (int j = 0; j < 4; ++j)
          acc[i][j] = MFMA(af[i], bfr[j], acc[i][j]);
    }
  }

  // C/D layout: col = lane&15, row = (lane>>4)*4 + r
  float* Eb = g_Ep + (((size_t)kc * 3 + s) * B_ + b) * (size_t)C_ * C_;
  const int orow0 = tile_m + wm + (lane >> 4) * 4;
  const int ocol0 = tile_d + wd + (lane & 15);
#pragma unroll
  for (int i = 0; i < 4; ++i)
#pragma unroll
    for (int j = 0; j < 4; ++j)
#pragma unroll
      for (int r = 0; r < 4; ++r)
        Eb[(size_t)(orow0 + i * 16 + r) * C_ + (ocol0 + j * 16)] = acc[i][j][r];
}

// ---------------------------------------------------------------------------
// Kernel 2: attnT[b][d][c] = sum_s exp(min_d E_s - E_s[c,d]) / Z_s   (bf16)
// One wave per c-row (4 rows/block), shuffle reductions, sums KSPLIT partials.
// grid (C/4, B).
// ---------------------------------------------------------------------------
__global__ __launch_bounds__(256) void softmax_kernel()
{
  const int b    = blockIdx.y;
  const int c    = blockIdx.x * 4 + (threadIdx.x >> 6);
  const int lane = threadIdx.x & 63;
  const int d0   = lane * 4;

  float a0 = 0.f, a1 = 0.f, a2 = 0.f, a3 = 0.f;
#pragma unroll
  for (int s = 0; s < 3; ++s) {
    float e0 = 0.f, e1 = 0.f, e2 = 0.f, e3 = 0.f;
#pragma unroll
    for (int kc = 0; kc < KSPLIT; ++kc) {
      const float4 ep = *(const float4*)(
          g_Ep + ((((size_t)kc * 3 + s) * B_ + b) * C_ + c) * (size_t)C_ + d0);
      e0 += ep.x; e1 += ep.y; e2 += ep.z; e3 += ep.w;
    }
    float mn = fminf(fminf(e0, e1), fminf(e2, e3));
#pragma unroll
    for (int m = 32; m > 0; m >>= 1) mn = fminf(mn, __shfl_xor(mn, m));
    const float p0 = __expf(mn - e0);   // <= 1; min term gives exactly 1
    const float p1 = __expf(mn - e1);
    const float p2 = __expf(mn - e2);
    const float p3 = __expf(mn - e3);
    float Z = p0 + p1 + p2 + p3;
#pragma unroll
    for (int m = 32; m > 0; m >>= 1) Z += __shfl_xor(Z, m);
    const float rZ = 1.0f / Z;
    a0 += p0 * rZ; a1 += p1 * rZ; a2 += p2 * rZ; a3 += p3 * rZ;
  }
  bf16_t* At = g_attnT + (size_t)b * C_ * C_;   // [d][c], transposed for mconv
  At[(size_t)(d0 + 0) * C_ + c] = (bf16_t)a0;
  At[(size_t)(d0 + 1) * C_ + c] = (bf16_t)a1;
  At[(size_t)(d0 + 2) * C_ + c] = (bf16_t)a2;
  At[(size_t)(d0 + 3) * C_ + c] = (bf16_t)a3;
}

// ---------------------------------------------------------------------------
// Kernel 3: M[b][o][d] = sum_c conv_w[o,c] * attnT[b][d][c]   (bf16 out)
// 64x64 tiles, 4 waves of 32x32, grid (16, B) = 256 blocks (1/CU).
// ---------------------------------------------------------------------------
__global__ __launch_bounds__(256) void mconv_kernel()
{
  const int tile = blockIdx.x;  // 0..15
  const int b    = blockIdx.y;
  const int tile_o = (tile & 3) * 64;
  const int tile_d = (tile >> 2) * 64;
  const int tid  = threadIdx.x;
  const int w    = tid >> 6;
  const int lane = tid & 63;
  const int wo   = (w & 1) * 32;
  const int wd   = (w >> 1) * 32;
  const int lrow = lane & 15;
  const int lk   = (lane >> 4) * 8;

  const bf16_t* At = g_attnT + (size_t)b * C_ * C_;
  f32x4 acc[2][2] = {};

  for (int c0 = 0; c0 < C_; c0 += 32) {
    bf16x8 af[2], bfr[2];
#pragma unroll
    for (int i = 0; i < 2; ++i)
      af[i] = *(const bf16x8*)(g_cw + (size_t)(tile_o + wo + i * 16 + lrow) * C_ + c0 + lk);
#pragma unroll
    for (int j = 0; j < 2; ++j)
      bfr[j] = *(const bf16x8*)(At + (size_t)(tile_d + wd + j * 16 + lrow) * C_ + c0 + lk);
#pragma unroll
    for (int i = 0; i < 2; ++i)
#pragma unroll
      for (int j = 0; j < 2; ++j)
        acc[i][j] = MFMA(af[i], bfr[j], acc[i][j]);
  }

  bf16_t* Mb = g_M + (size_t)b * C_ * C_;
  const int orow0 = tile_o + wo + (lane >> 4) * 4;
  const int ocol0 = tile_d + wd + (lane & 15);
#pragma unroll
  for (int i = 0; i < 2; ++i)
#pragma unroll
    for (int j = 0; j < 2; ++j)
#pragma unroll
      for (int r = 0; r < 2 * 2; ++r)
        Mb[(size_t)(orow0 + i * 16 + r) * C_ + (ocol0 + j * 16)] = (bf16_t)acc[i][j][r];
}

// ---------------------------------------------------------------------------
// Kernel 4a: P[b][o][n] = sum_d M[b,o,d] * Q[b,d,n]   (bf16 out)
// Reg-staged NT: A rows = M[o][d], B rows = qT[n][d], BK=64. grid (N/128,2,B).
// ---------------------------------------------------------------------------
__global__ __launch_bounds__(256) void pmq_kernel()
{
  const int tile_n = blockIdx.x * 128;          // 0..31
  const int tile_o = blockIdx.y * 128;          // 0..1
  const int b      = blockIdx.z;

  const bf16_t* Mb = g_M  + (size_t)b * C_ * C_;
  const bf16_t* Qt = g_qT + (size_t)b * N_ * C_;

  __shared__ bf16_t As[128][72];  // M rows   [o][d]
  __shared__ bf16_t Bs[128][72];  // qT rows  [n][d]

  const int tid  = threadIdx.x;
  const int w    = tid >> 6;
  const int lane = tid & 63;
  const int wo   = (w & 1) * 64;
  const int wn   = (w >> 1) * 64;
  const int lrow = lane & 15;
  const int lk   = (lane >> 4) * 8;

  const int srow = tid >> 3;        // 0..31
  const int soff = (tid & 7) * 8;   // 0..56

  f32x4 acc[4][4] = {};

  for (int d0 = 0; d0 < C_; d0 += 64) {
    bf16x8 av[4], bv[4];
#pragma unroll
    for (int i = 0; i < 4; ++i) {
      int r = srow + i * 32;
      av[i] = *(const bf16x8*)(Mb + (size_t)(tile_o + r) * C_ + d0 + soff);
      bv[i] = *(const bf16x8*)(Qt + (size_t)(tile_n + r) * C_ + d0 + soff);
    }
    __syncthreads();
#pragma unroll
    for (int i = 0; i < 4; ++i) {
      int r = srow + i * 32;
      *(bf16x8*)(&As[r][soff]) = av[i];
      *(bf16x8*)(&Bs[r][soff]) = bv[i];
    }
    __syncthreads();
#pragma unroll
    for (int kk = 0; kk < 64; kk += 32) {
      bf16x8 af[4], bfr[4];
#pragma unroll
      for (int i = 0; i < 4; ++i)
        af[i] = *(const bf16x8*)(&As[wo + i * 16 + lrow][kk + lk]);
#pragma unroll
      for (int j = 0; j < 4; ++j)
        bfr[j] = *(const bf16x8*)(&Bs[wn + j * 16 + lrow][kk + lk]);
#pragma unroll
      for (int i = 0; i < 4; ++i)
#pragma unroll
        for (int j = 0; j < 4; ++j)
          acc[i][j] = MFMA(af[i], bfr[j], acc[i][j]);
    }
  }

  // C/D layout: col = lane&15 (n), row = (lane>>4)*4 + r (o)
  bf16_t* Pb = g_P + (size_t)b * C_ * N_;
  const int orow0 = tile_o + wo + (lane >> 4) * 4;
  const int ocol0 = tile_n + wn + (lane & 15);
#pragma unroll
  for (int i = 0; i < 4; ++i)
#pragma unroll
    for (int j = 0; j < 4; ++j)
#pragma unroll
      for (int r = 0; r < 4; ++r)
        Pb[(size_t)(orow0 + i * 16 + r) * N_ + (ocol0 + j * 16)] = (bf16_t)acc[i][j][r];
}

// ---------------------------------------------------------------------------
// Kernel 4b: out[b][o][n] = gamma*(P[b,o,n] + bias[o]) + x[b,o,n]
// Pure streaming; one block per (b,o) row; 16 elems/thread, vector I/O.
// grid (B*C).
// ---------------------------------------------------------------------------
__global__ __launch_bounds__(256) void epilogue_kernel(
    const void* __restrict__ xraw, void* __restrict__ outraw)
{
  const int row  = blockIdx.x;            // b*C_ + o
  const int o    = row & (C_ - 1);
  const size_t roff = (size_t)row * N_ + (size_t)threadIdx.x * 16;

  const float g    = g_gamma;
  const float bias = g_cb[o];

  const bf16x8 p0 = *(const bf16x8*)(g_P + roff);
  const bf16x8 p1 = *(const bf16x8*)(g_P + roff + 8);
  float v[16];
#pragma unroll
  for (int k = 0; k < 8; ++k) {
    v[k]     = g * ((float)p0[k] + bias);
    v[8 + k] = g * ((float)p1[k] + bias);
  }

  if (g_mode == MODE_F32) {
    const float* xp = (const float*)xraw + roff;
    float*       op = (float*)outraw + roff;
#pragma unroll
    for (int q4 = 0; q4 < 4; ++q4) {
      float4 xv = *(const float4*)(xp + q4 * 4);
      float4 ov;
      ov.x = v[q4 * 4 + 0] + xv.x;
      ov.y = v[q4 * 4 + 1] + xv.y;
      ov.z = v[q4 * 4 + 2] + xv.z;
      ov.w = v[q4 * 4 + 3] + xv.w;
      *(float4*)(op + q4 * 4) = ov;
    }
  } else {
    const bf16_t* xp = (const bf16_t*)xraw + roff;
    bf16_t*       op = (bf16_t*)outraw + roff;
#pragma unroll
    for (int p = 0; p < 2; ++p) {
      bf16x8 xv = *(const bf16x8*)(xp + p * 8);
      bf16x8 ov;
#pragma unroll
      for (int k = 0; k < 8; ++k)
        ov[k] = (bf16_t)(v[p * 8 + k] + (float)xv[k]);
      *(bf16x8*)(op + p * 8) = ov;
    }
  }
}

// ---------------------------------------------------------------------------
extern "C" void kernel_launch(void* const* d_in, const int* in_sizes, int n_in,
                              void* d_out, int out_size, void* d_ws, size_t ws_size,
                              hipStream_t stream)
{
  const void* x  = d_in[0];
  const void* y  = d_in[1];
  const void* z  = d_in[2];
  const void* cw = d_in[3];
  const void* cb = d_in[4];
  const void* gm = d_in[5];
  (void)d_ws; (void)ws_size;

  setup_kernel    <<<1,                       256, 0, stream>>>((const float*)x, cw, cb, gm);
  convert_xT      <<<dim3(N_ / 64, C_ / 64, B_), 256, 0, stream>>>(x);
  energy_kernel   <<<dim3(4 * KSPLIT, 3, B_), 256, 0, stream>>>(x, y, z);
  softmax_kernel  <<<dim3(C_ / 4, B_),        256, 0, stream>>>();
  mconv_kernel    <<<dim3(16, B_),            256, 0, stream>>>();
  pmq_kernel      <<<dim3(N_ / 128, 2, B_),   256, 0, stream>>>();
  epilogue_kernel <<<dim3(B_ * C_),           256, 0, stream>>>(x, d_out);
}

// Round 6
// 356.650 us; speedup vs baseline: 1.1559x; 1.0492x over previous
//
#include <hip/hip_runtime.h>
#include <hip/hip_bf16.h>

// Problem: B=16, C=256, H=W=64 -> N=4096.
// ref: attn = sum_s softmax(max-E_s) over last dim, E_s = Q K_s^T (reduce over N)
//      out  = gamma * (conv_w @ (attn @ Q) + bias) + x
// fused as: M = conv_w @ attn  (tiny GEMM), P = M @ Q, out = gamma*(P+bias)+x
//
// v7 changes vs v6 (374 us):
//  - energy (93 us, FETCH 252 MB vs 160 in v3: cold raw inputs + panel
//    re-reads scattered across XCD L2s): XCD-chunked blockIdx swizzle (T1).
//    Grid flattened to 1D-768; each XCD chunk enumerates tile->s->kc->b, so
//    the 12 blocks sharing one (b,kc) panel group are consecutive -> panels
//    fetched once per XCD L2 instead of ~6x from HBM.
//  - epilogue_kernel FUSED into pmq via LDS repack (acc -> bf16 [128][136]
//    LDS tile aliasing the staging buffers -> vectorized read-back adding
//    gamma*(P+bias)+x with coalesced 16B global I/O). Removes the P buffer
//    round-trip (67 MB), the scalar-scattered P store, and one launch.
//    Same bf16 rounding point as before -> numerics unchanged.
//  - pmq also XCD-swizzled (2-b chunks: qT re-read x2 -> x1 per XCD).

#define B_ 16
#define C_ 256
#define N_ 4096
#define KSPLIT 4
#define KCHUNK (N_ / KSPLIT)   // 1024

#define MODE_BF16 0
#define MODE_F32  1

typedef __bf16 bf16_t;
typedef bf16_t bf16x8 __attribute__((ext_vector_type(8)));
typedef float  f32x4  __attribute__((ext_vector_type(4)));

#define MFMA(a, b, c) __builtin_amdgcn_mfma_f32_16x16x32_bf16(a, b, c, 0, 0, 0)

// Scratch (module-load allocated; no ws_size dependence; graph-safe).
__device__ int    g_mode;
__device__ bf16_t g_q[(size_t)B_ * C_ * N_];       // canonical x (F32 mode only)
__device__ bf16_t g_qT[(size_t)B_ * N_ * C_];      // x^T [b][n][c] (33.5 MB)
__device__ bf16_t g_cw[C_ * C_];
__device__ float  g_cb[C_];
__device__ float  g_gamma;
__device__ float  g_Ep[(size_t)KSPLIT * 3 * B_ * C_ * C_];  // partial E, 50.3 MB
__device__ bf16_t g_attnT[(size_t)B_ * C_ * C_];
__device__ bf16_t g_M[(size_t)B_ * C_ * C_];

// ---------------------------------------------------------------------------
// Kernel 0: dtype sniff + param canonicalization, one block.
// fp32 N(0,1) -> abs bits <= ~0x40C00000; bf16 pair misread as fp32 ~1e37.
// ---------------------------------------------------------------------------
__global__ __launch_bounds__(256) void setup_kernel(
    const float* __restrict__ xf, const void* __restrict__ cw,
    const void* __restrict__ cb, const void* __restrict__ gm)
{
  __shared__ unsigned red[256];
  const int t = threadIdx.x;
  unsigned m = 0;
  for (int i = t; i < 4096; i += 256)
    m = max(m, __float_as_uint(xf[i]) & 0x7fffffffu);
  red[t] = m;
  __syncthreads();
  for (int s = 128; s > 0; s >>= 1) {
    if (t < s) red[t] = max(red[t], red[t + s]);
    __syncthreads();
  }
  const int mode = (red[0] > 0x44800000u) ? MODE_BF16 : MODE_F32;
  if (t == 0) g_mode = mode;

  if (mode == MODE_F32) {
    for (int i = t * 8; i < C_ * C_; i += 256 * 8) {
      const float* s = (const float*)cw + i;
      float4 a = *(const float4*)s;
      float4 b = *(const float4*)(s + 4);
      bf16x8 v;
      v[0] = (bf16_t)a.x; v[1] = (bf16_t)a.y; v[2] = (bf16_t)a.z; v[3] = (bf16_t)a.w;
      v[4] = (bf16_t)b.x; v[5] = (bf16_t)b.y; v[6] = (bf16_t)b.z; v[7] = (bf16_t)b.w;
      *(bf16x8*)(g_cw + i) = v;
    }
    if (t < C_) g_cb[t] = ((const float*)cb)[t];
    if (t == 0) g_gamma = ((const float*)gm)[0];
  } else {
    for (int i = t * 8; i < C_ * C_; i += 256 * 8)
      *(bf16x8*)(g_cw + i) = *(const bf16x8*)((const bf16_t*)cw + i);
    if (t < C_) g_cb[t] = (float)((const bf16_t*)cb)[t];
    if (t == 0) g_gamma = (float)((const bf16_t*)gm)[0];
  }
}

// ---------------------------------------------------------------------------
// Kernel 0d: materialize x^T [b][n][c] bf16 (and g_q bf16 copy in F32 mode).
// 64x64 tiles via XOR-swizzled LDS; both store and transposed read are
// bank-conflict-free. grid (N/64, C/64, B).
// ---------------------------------------------------------------------------
__global__ __launch_bounds__(256) void convert_xT(const void* __restrict__ x)
{
  __shared__ bf16_t Ts[64][64];   // [c_local][n_swizzled], 8 KB
  const int t  = threadIdx.x;
  const int r  = t >> 3;          // 0..31
  const int nb = t & 7;           // n-block / c-block index
  const int co = nb * 8;
  const int n0 = blockIdx.x * 64;
  const int c0 = blockIdx.y * 64;
  const int b  = blockIdx.z;
  const size_t base = (size_t)b * C_ * N_;
  const int mode = g_mode;

  bf16x8 v[2];
  if (mode == MODE_F32) {
#pragma unroll
    for (int p = 0; p < 2; ++p) {
      const float* s = (const float*)x + base + (size_t)(c0 + r + p * 32) * N_ + n0 + co;
      float4 a = *(const float4*)s;
      float4 b4 = *(const float4*)(s + 4);
      bf16x8 w;
      w[0] = (bf16_t)a.x; w[1] = (bf16_t)a.y; w[2] = (bf16_t)a.z; w[3] = (bf16_t)a.w;
      w[4] = (bf16_t)b4.x; w[5] = (bf16_t)b4.y; w[6] = (bf16_t)b4.z; w[7] = (bf16_t)b4.w;
      v[p] = w;
    }
  } else {
#pragma unroll
    for (int p = 0; p < 2; ++p)
      v[p] = *(const bf16x8*)((const bf16_t*)x + base + (size_t)(c0 + r + p * 32) * N_ + n0 + co);
  }

#pragma unroll
  for (int p = 0; p < 2; ++p) {
    const int cl = r + p * 32;
    if (mode == MODE_F32)   // bf16 canonical copy needed only in F32 mode
      *(bf16x8*)(g_q + base + (size_t)(c0 + cl) * N_ + n0 + co) = v[p];
    const int swz = nb ^ ((cl >> 3) & 7);
    *(bf16x8*)(&Ts[cl][swz * 8]) = v[p];
  }
  __syncthreads();

  // transposed read: QT[b][n0+nl][c0+co .. +7]
#pragma unroll
  for (int p = 0; p < 2; ++p) {
    const int nl = r + p * 32;
    bf16x8 w;
#pragma unroll
    for (int j = 0; j < 8; ++j) {
      const int c = co + j;
      const int k = (c >> 3) & 7;   // == nb
      w[j] = Ts[c][(((nl >> 3) ^ k) * 8) + (nl & 7)];
    }
    *(bf16x8*)(g_qT + (size_t)b * N_ * C_ + (size_t)(n0 + nl) * C_ + c0 + co) = w;
  }
}

// ---------------------------------------------------------------------------
// Kernel 1: Ep[kc][s][b][c][d] = sum_{n in chunk} Q[b,c,n] * Ksrc_s[b,d,n]
// 128x128 tile, 4 waves of 64x64, BK=64, reg-staged padded LDS, K split x4.
// 1D grid 768, XCD-chunked swizzle: chunk = 96 blocks/XCD enumerating
// tile (fastest) -> s -> kc -> b, so the 12 blocks sharing a (b,kc) panel
// group land on one XCD's L2.
// ---------------------------------------------------------------------------
__global__ __launch_bounds__(256) void energy_kernel(
    const void* __restrict__ xraw, const void* __restrict__ yraw,
    const void* __restrict__ zraw)
{
  const int id   = blockIdx.x;                 // 0..767
  const int swz  = (id & 7) * 96 + (id >> 3);  // XCD x gets [x*96, x*96+96)
  const int tile = swz & 3;                    // 0..3
  const int s    = (swz >> 2) % 3;             // 0..2
  const int kc   = (swz / 12) & 3;             // 0..3
  const int b    = swz / 48;                   // 0..15

  const int mode = g_mode;
  const bf16_t* q =
      (mode == MODE_BF16 ? (const bf16_t*)xraw : g_q) + (size_t)b * C_ * N_;

  const bf16_t* kb16 = nullptr;
  const float*  kf32 = nullptr;
  if (s == 0) {
    kb16 = q;
  } else if (mode == MODE_BF16) {
    kb16 = (const bf16_t*)(s == 1 ? yraw : zraw) + (size_t)b * C_ * N_;
  } else {
    kf32 = (const float*)(s == 1 ? yraw : zraw) + (size_t)b * C_ * N_;
  }

  const int tile_m = (tile & 1) * 128;
  const int tile_d = (tile >> 1) * 128;

  __shared__ bf16_t As[128][72];  // stride 144 B: 16B-aligned rows, non-pow2
  __shared__ bf16_t Bs[128][72];

  const int tid  = threadIdx.x;
  const int w    = tid >> 6;
  const int lane = tid & 63;
  const int wm   = (w & 1) * 64;
  const int wd   = (w >> 1) * 64;
  const int lrow = lane & 15;
  const int lk   = (lane >> 4) * 8;

  const int srow = tid >> 3;        // 0..31
  const int soff = (tid & 7) * 8;   // 0..56

  f32x4 acc[4][4] = {};

  const int kbeg = kc * KCHUNK;
  for (int k0 = kbeg; k0 < kbeg + KCHUNK; k0 += 64) {
    bf16x8 av[4], bv[4];
#pragma unroll
    for (int i = 0; i < 4; ++i) {
      int r = srow + i * 32;
      av[i] = *(const bf16x8*)(q + (size_t)(tile_m + r) * N_ + k0 + soff);
    }
    if (kf32) {
#pragma unroll
      for (int i = 0; i < 4; ++i) {
        int r = srow + i * 32;
        const float* sp = kf32 + (size_t)(tile_d + r) * N_ + k0 + soff;
        float4 a = *(const float4*)sp;
        float4 c = *(const float4*)(sp + 4);
        bf16x8 v;
        v[0] = (bf16_t)a.x; v[1] = (bf16_t)a.y; v[2] = (bf16_t)a.z; v[3] = (bf16_t)a.w;
        v[4] = (bf16_t)c.x; v[5] = (bf16_t)c.y; v[6] = (bf16_t)c.z; v[7] = (bf16_t)c.w;
        bv[i] = v;
      }
    } else {
#pragma unroll
      for (int i = 0; i < 4; ++i) {
        int r = srow + i * 32;
        bv[i] = *(const bf16x8*)(kb16 + (size_t)(tile_d + r) * N_ + k0 + soff);
      }
    }
    __syncthreads();   // prior iter's LDS reads complete before overwrite
#pragma unroll
    for (int i = 0; i < 4; ++i) {
      int r = srow + i * 32;
      *(bf16x8*)(&As[r][soff]) = av[i];
      *(bf16x8*)(&Bs[r][soff]) = bv[i];
    }
    __syncthreads();
#pragma unroll
    for (int kk = 0; kk < 64; kk += 32) {
      bf16x8 af[4], bfr[4];
#pragma unroll
      for (int i = 0; i < 4; ++i)
        af[i] = *(const bf16x8*)(&As[wm + i * 16 + lrow][kk + lk]);
#pragma unroll
      for (int j = 0; j < 4; ++j)
        bfr[j] = *(const bf16x8*)(&Bs[wd + j * 16 + lrow][kk + lk]);
#pragma unroll
      for (int i = 0; i < 4; ++i)
#pragma unroll
        for (int j = 0; j < 4; ++j)
          acc[i][j] = MFMA(af[i], bfr[j], acc[i][j]);
    }
  }

  // C/D layout: col = lane&15, row = (lane>>4)*4 + r
  float* Eb = g_Ep + (((size_t)kc * 3 + s) * B_ + b) * (size_t)C_ * C_;
  const int orow0 = tile_m + wm + (lane >> 4) * 4;
  const int ocol0 = tile_d + wd + (lane & 15);
#pragma unroll
  for (int i = 0; i < 4; ++i)
#pragma unroll
    for (int j = 0; j < 4; ++j)
#pragma unroll
      for (int r = 0; r < 4; ++r)
        Eb[(size_t)(orow0 + i * 16 + r) * C_ + (ocol0 + j * 16)] = acc[i][j][r];
}

// ---------------------------------------------------------------------------
// Kernel 2: attnT[b][d][c] = sum_s exp(min_d E_s - E_s[c,d]) / Z_s   (bf16)
// One wave per c-row (4 rows/block), shuffle reductions, sums KSPLIT partials.
// grid (C/4, B).
// ---------------------------------------------------------------------------
__global__ __launch_bounds__(256) void softmax_kernel()
{
  const int b    = blockIdx.y;
  const int c    = blockIdx.x * 4 + (threadIdx.x >> 6);
  const int lane = threadIdx.x & 63;
  const int d0   = lane * 4;

  float a0 = 0.f, a1 = 0.f, a2 = 0.f, a3 = 0.f;
#pragma unroll
  for (int s = 0; s < 3; ++s) {
    float e0 = 0.f, e1 = 0.f, e2 = 0.f, e3 = 0.f;
#pragma unroll
    for (int kc = 0; kc < KSPLIT; ++kc) {
      const float4 ep = *(const float4*)(
          g_Ep + ((((size_t)kc * 3 + s) * B_ + b) * C_ + c) * (size_t)C_ + d0);
      e0 += ep.x; e1 += ep.y; e2 += ep.z; e3 += ep.w;
    }
    float mn = fminf(fminf(e0, e1), fminf(e2, e3));
#pragma unroll
    for (int m = 32; m > 0; m >>= 1) mn = fminf(mn, __shfl_xor(mn, m));
    const float p0 = __expf(mn - e0);   // <= 1; min term gives exactly 1
    const float p1 = __expf(mn - e1);
    const float p2 = __expf(mn - e2);
    const float p3 = __expf(mn - e3);
    float Z = p0 + p1 + p2 + p3;
#pragma unroll
    for (int m = 32; m > 0; m >>= 1) Z += __shfl_xor(Z, m);
    const float rZ = 1.0f / Z;
    a0 += p0 * rZ; a1 += p1 * rZ; a2 += p2 * rZ; a3 += p3 * rZ;
  }
  bf16_t* At = g_attnT + (size_t)b * C_ * C_;   // [d][c], transposed for mconv
  At[(size_t)(d0 + 0) * C_ + c] = (bf16_t)a0;
  At[(size_t)(d0 + 1) * C_ + c] = (bf16_t)a1;
  At[(size_t)(d0 + 2) * C_ + c] = (bf16_t)a2;
  At[(size_t)(d0 + 3) * C_ + c] = (bf16_t)a3;
}

// ---------------------------------------------------------------------------
// Kernel 3: M[b][o][d] = sum_c conv_w[o,c] * attnT[b][d][c]   (bf16 out)
// 64x64 tiles, 4 waves of 32x32, grid (16, B) = 256 blocks (1/CU).
// ---------------------------------------------------------------------------
__global__ __launch_bounds__(256) void mconv_kernel()
{
  const int tile = blockIdx.x;  // 0..15
  const int b    = blockIdx.y;
  const int tile_o = (tile & 3) * 64;
  const int tile_d = (tile >> 2) * 64;
  const int tid  = threadIdx.x;
  const int w    = tid >> 6;
  const int lane = tid & 63;
  const int wo   = (w & 1) * 32;
  const int wd   = (w >> 1) * 32;
  const int lrow = lane & 15;
  const int lk   = (lane >> 4) * 8;

  const bf16_t* At = g_attnT + (size_t)b * C_ * C_;
  f32x4 acc[2][2] = {};

  for (int c0 = 0; c0 < C_; c0 += 32) {
    bf16x8 af[2], bfr[2];
#pragma unroll
    for (int i = 0; i < 2; ++i)
      af[i] = *(const bf16x8*)(g_cw + (size_t)(tile_o + wo + i * 16 + lrow) * C_ + c0 + lk);
#pragma unroll
    for (int j = 0; j < 2; ++j)
      bfr[j] = *(const bf16x8*)(At + (size_t)(tile_d + wd + j * 16 + lrow) * C_ + c0 + lk);
#pragma unroll
    for (int i = 0; i < 2; ++i)
#pragma unroll
      for (int j = 0; j < 2; ++j)
        acc[i][j] = MFMA(af[i], bfr[j], acc[i][j]);
  }

  bf16_t* Mb = g_M + (size_t)b * C_ * C_;
  const int orow0 = tile_o + wo + (lane >> 4) * 4;
  const int ocol0 = tile_d + wd + (lane & 15);
#pragma unroll
  for (int i = 0; i < 2; ++i)
#pragma unroll
    for (int j = 0; j < 2; ++j)
#pragma unroll
      for (int r = 0; r < 4; ++r)
        Mb[(size_t)(orow0 + i * 16 + r) * C_ + (ocol0 + j * 16)] = (bf16_t)acc[i][j][r];
}

// ---------------------------------------------------------------------------
// Kernel 4: P-tile = M @ Q^T with FUSED epilogue:
//   out[b][o][n] = gamma*(bf16(acc) + bias[o]) + x[b][o][n]
// Reg-staged NT GEMM (A rows = M[o][d], B rows = qT[n][d], BK=64), then the
// acc tile is repacked bf16 into LDS (aliasing the staging buffers, padded
// [128][136]) and read back with coalesced 16B global I/O.
// 1D grid 1024, XCD-chunked swizzle (o fastest -> n -> b; 2 b per XCD chunk).
// Dynamic LDS = 36864 B.
// ---------------------------------------------------------------------------
__global__ __launch_bounds__(256) void pmq_kernel(
    const void* __restrict__ xraw, void* __restrict__ outraw)
{
  extern __shared__ char smraw[];
  bf16_t* sm = (bf16_t*)smraw;
  bf16_t (*As)[72]  = (bf16_t(*)[72])sm;              // [128][72] M rows
  bf16_t (*Bs)[72]  = (bf16_t(*)[72])(sm + 128 * 72); // [128][72] qT rows
  bf16_t (*Os)[136] = (bf16_t(*)[136])sm;             // [128][136] out tile (reuse)

  const int id  = blockIdx.x;                  // 0..1023
  const int swz = (id & 7) * 128 + (id >> 3);  // XCD-chunked
  const int tile_o = (swz & 1) * 128;
  const int tile_n = ((swz >> 1) & 31) * 128;
  const int b      = swz >> 6;

  const bf16_t* Mb = g_M  + (size_t)b * C_ * C_;
  const bf16_t* Qt = g_qT + (size_t)b * N_ * C_;

  const int tid  = threadIdx.x;
  const int w    = tid >> 6;
  const int lane = tid & 63;
  const int wo   = (w & 1) * 64;
  const int wn   = (w >> 1) * 64;
  const int lrow = lane & 15;
  const int lk   = (lane >> 4) * 8;

  const int srow = tid >> 3;        // 0..31
  const int soff = (tid & 7) * 8;   // 0..56

  f32x4 acc[4][4] = {};

  for (int d0 = 0; d0 < C_; d0 += 64) {
    bf16x8 av[4], bv[4];
#pragma unroll
    for (int i = 0; i < 4; ++i) {
      int r = srow + i * 32;
      av[i] = *(const bf16x8*)(Mb + (size_t)(tile_o + r) * C_ + d0 + soff);
      bv[i] = *(const bf16x8*)(Qt + (size_t)(tile_n + r) * C_ + d0 + soff);
    }
    __syncthreads();
#pragma unroll
    for (int i = 0; i < 4; ++i) {
      int r = srow + i * 32;
      *(bf16x8*)(&As[r][soff]) = av[i];
      *(bf16x8*)(&Bs[r][soff]) = bv[i];
    }
    __syncthreads();
#pragma unroll
    for (int kk = 0; kk < 64; kk += 32) {
      bf16x8 af[4], bfr[4];
#pragma unroll
      for (int i = 0; i < 4; ++i)
        af[i] = *(const bf16x8*)(&As[wo + i * 16 + lrow][kk + lk]);
#pragma unroll
      for (int j = 0; j < 4; ++j)
        bfr[j] = *(const bf16x8*)(&Bs[wn + j * 16 + lrow][kk + lk]);
#pragma unroll
      for (int i = 0; i < 4; ++i)
#pragma unroll
        for (int j = 0; j < 4; ++j)
          acc[i][j] = MFMA(af[i], bfr[j], acc[i][j]);
    }
  }

  // ---- fused epilogue ----
  __syncthreads();   // all waves done with As/Bs before aliasing as Os

  // scatter acc (bf16-rounded, same rounding point as the old P store)
  const int orow0 = wo + (lane >> 4) * 4;   // local row in 128-tile
  const int ocol0 = wn + (lane & 15);
#pragma unroll
  for (int i = 0; i < 4; ++i)
#pragma unroll
    for (int j = 0; j < 4; ++j)
#pragma unroll
      for (int r = 0; r < 4; ++r)
        Os[orow0 + i * 16 + r][ocol0 + j * 16] = (bf16_t)acc[i][j][r];
  __syncthreads();

  // coalesced read-back: pass p covers rows p*16 + (tid>>4), 16 lanes span a
  // 256 B row segment (16B/lane).
  const float g   = g_gamma;
  const int mode  = g_mode;
  const int rr    = tid >> 4;          // 0..15
  const int cc    = (tid & 15) * 8;    // 0..120
  const size_t gbase = (size_t)b * C_ * N_;

#pragma unroll
  for (int p = 0; p < 8; ++p) {
    const int r = p * 16 + rr;
    const float bias = g_cb[tile_o + r];
    const bf16x8 sv = *(const bf16x8*)(&Os[r][cc]);
    const size_t off = gbase + (size_t)(tile_o + r) * N_ + tile_n + cc;
    if (mode == MODE_F32) {
      const float* xp = (const float*)xraw + off;
      float*       op = (float*)outraw + off;
#pragma unroll
      for (int q4 = 0; q4 < 2; ++q4) {
        float4 xv = *(const float4*)(xp + q4 * 4);
        float4 ov;
        ov.x = g * ((float)sv[q4 * 4 + 0] + bias) + xv.x;
        ov.y = g * ((float)sv[q4 * 4 + 1] + bias) + xv.y;
        ov.z = g * ((float)sv[q4 * 4 + 2] + bias) + xv.z;
        ov.w = g * ((float)sv[q4 * 4 + 3] + bias) + xv.w;
        *(float4*)(op + q4 * 4) = ov;
      }
    } else {
      const bf16_t* xp = (const bf16_t*)xraw + off;
      bf16_t*       op = (bf16_t*)outraw + off;
      const bf16x8 xv = *(const bf16x8*)xp;
      bf16x8 ov;
#pragma unroll
      for (int k = 0; k < 8; ++k)
        ov[k] = (bf16_t)(g * ((float)sv[k] + bias) + (float)xv[k]);
      *(bf16x8*)op = ov;
    }
  }
}

// ---------------------------------------------------------------------------
extern "C" void kernel_launch(void* const* d_in, const int* in_sizes, int n_in,
                              void* d_out, int out_size, void* d_ws, size_t ws_size,
                              hipStream_t stream)
{
  const void* x  = d_in[0];
  const void* y  = d_in[1];
  const void* z  = d_in[2];
  const void* cw = d_in[3];
  const void* cb = d_in[4];
  const void* gm = d_in[5];
  (void)d_ws; (void)ws_size;

  setup_kernel   <<<1,                          256, 0, stream>>>((const float*)x, cw, cb, gm);
  convert_xT     <<<dim3(N_ / 64, C_ / 64, B_), 256, 0, stream>>>(x);
  energy_kernel  <<<dim3(4 * KSPLIT * 3 * B_),  256, 0, stream>>>(x, y, z);
  softmax_kernel <<<dim3(C_ / 4, B_),           256, 0, stream>>>();
  mconv_kernel   <<<dim3(16, B_),               256, 0, stream>>>();
  pmq_kernel     <<<dim3(N_ / 128 * 2 * B_),    256, 36864, stream>>>(x, d_out);
}

// Round 7
// 347.154 us; speedup vs baseline: 1.1875x; 1.0274x over previous
//
#include <hip/hip_runtime.h>
#include <hip/hip_bf16.h>

// Problem: B=16, C=256, H=W=64 -> N=4096.
// ref: attn = sum_s softmax(max-E_s) over last dim, E_s = Q K_s^T (reduce over N)
//      out  = gamma * (conv_w @ (attn @ Q) + bias) + x
// fused as: M = conv_w @ attn  (tiny GEMM), P = M @ Q, out = gamma*(P+bias)+x
//
// v8 changes vs v7 (356.7 us):
//  - energy (91.8 us, 280 TF, latency-bound: loads issued then immediately
//    vmcnt-waited by ds_write every K-step): 2-deep REGISTER PREFETCH
//    (T14 issue-early/write-late). Manually unrolled x2 ping-pong (named reg
//    sets avA/avB -- no runtime-indexed arrays), loads for step t+1 issued
//    right after barrier #1 of step t, so ds_write(t) waits on loads that
//    have had a full MFMA phase + 2 barriers to complete. Single LDS buffer,
//    same barrier count. XCD swizzle kept (FETCH 252->89 MB confirmed).
//  - pmq: same 2-deep prefetch on its 4-step d-loop. Fused epilogue kept.
//  - No numeric changes (same rounding points everywhere).

#define B_ 16
#define C_ 256
#define N_ 4096
#define KSPLIT 4
#define KCHUNK (N_ / KSPLIT)   // 1024

#define MODE_BF16 0
#define MODE_F32  1

typedef __bf16 bf16_t;
typedef bf16_t bf16x8 __attribute__((ext_vector_type(8)));
typedef float  f32x4  __attribute__((ext_vector_type(4)));

#define MFMA(a, b, c) __builtin_amdgcn_mfma_f32_16x16x32_bf16(a, b, c, 0, 0, 0)

// Scratch (module-load allocated; no ws_size dependence; graph-safe).
__device__ int    g_mode;
__device__ bf16_t g_q[(size_t)B_ * C_ * N_];       // canonical x (F32 mode only)
__device__ bf16_t g_qT[(size_t)B_ * N_ * C_];      // x^T [b][n][c] (33.5 MB)
__device__ bf16_t g_cw[C_ * C_];
__device__ float  g_cb[C_];
__device__ float  g_gamma;
__device__ float  g_Ep[(size_t)KSPLIT * 3 * B_ * C_ * C_];  // partial E, 50.3 MB
__device__ bf16_t g_attnT[(size_t)B_ * C_ * C_];
__device__ bf16_t g_M[(size_t)B_ * C_ * C_];

// ---------------------------------------------------------------------------
// Kernel 0: dtype sniff + param canonicalization, one block.
// ---------------------------------------------------------------------------
__global__ __launch_bounds__(256) void setup_kernel(
    const float* __restrict__ xf, const void* __restrict__ cw,
    const void* __restrict__ cb, const void* __restrict__ gm)
{
  __shared__ unsigned red[256];
  const int t = threadIdx.x;
  unsigned m = 0;
  for (int i = t; i < 4096; i += 256)
    m = max(m, __float_as_uint(xf[i]) & 0x7fffffffu);
  red[t] = m;
  __syncthreads();
  for (int s = 128; s > 0; s >>= 1) {
    if (t < s) red[t] = max(red[t], red[t + s]);
    __syncthreads();
  }
  const int mode = (red[0] > 0x44800000u) ? MODE_BF16 : MODE_F32;
  if (t == 0) g_mode = mode;

  if (mode == MODE_F32) {
    for (int i = t * 8; i < C_ * C_; i += 256 * 8) {
      const float* s = (const float*)cw + i;
      float4 a = *(const float4*)s;
      float4 b = *(const float4*)(s + 4);
      bf16x8 v;
      v[0] = (bf16_t)a.x; v[1] = (bf16_t)a.y; v[2] = (bf16_t)a.z; v[3] = (bf16_t)a.w;
      v[4] = (bf16_t)b.x; v[5] = (bf16_t)b.y; v[6] = (bf16_t)b.z; v[7] = (bf16_t)b.w;
      *(bf16x8*)(g_cw + i) = v;
    }
    if (t < C_) g_cb[t] = ((const float*)cb)[t];
    if (t == 0) g_gamma = ((const float*)gm)[0];
  } else {
    for (int i = t * 8; i < C_ * C_; i += 256 * 8)
      *(bf16x8*)(g_cw + i) = *(const bf16x8*)((const bf16_t*)cw + i);
    if (t < C_) g_cb[t] = (float)((const bf16_t*)cb)[t];
    if (t == 0) g_gamma = (float)((const bf16_t*)gm)[0];
  }
}

// ---------------------------------------------------------------------------
// Kernel 0d: materialize x^T [b][n][c] bf16 (and g_q bf16 copy in F32 mode).
// 64x64 tiles via XOR-swizzled LDS; conflict-free both directions.
// grid (N/64, C/64, B).
// ---------------------------------------------------------------------------
__global__ __launch_bounds__(256) void convert_xT(const void* __restrict__ x)
{
  __shared__ bf16_t Ts[64][64];   // [c_local][n_swizzled], 8 KB
  const int t  = threadIdx.x;
  const int r  = t >> 3;          // 0..31
  const int nb = t & 7;           // n-block / c-block index
  const int co = nb * 8;
  const int n0 = blockIdx.x * 64;
  const int c0 = blockIdx.y * 64;
  const int b  = blockIdx.z;
  const size_t base = (size_t)b * C_ * N_;
  const int mode = g_mode;

  bf16x8 v[2];
  if (mode == MODE_F32) {
#pragma unroll
    for (int p = 0; p < 2; ++p) {
      const float* s = (const float*)x + base + (size_t)(c0 + r + p * 32) * N_ + n0 + co;
      float4 a = *(const float4*)s;
      float4 b4 = *(const float4*)(s + 4);
      bf16x8 w;
      w[0] = (bf16_t)a.x; w[1] = (bf16_t)a.y; w[2] = (bf16_t)a.z; w[3] = (bf16_t)a.w;
      w[4] = (bf16_t)b4.x; w[5] = (bf16_t)b4.y; w[6] = (bf16_t)b4.z; w[7] = (bf16_t)b4.w;
      v[p] = w;
    }
  } else {
#pragma unroll
    for (int p = 0; p < 2; ++p)
      v[p] = *(const bf16x8*)((const bf16_t*)x + base + (size_t)(c0 + r + p * 32) * N_ + n0 + co);
  }

#pragma unroll
  for (int p = 0; p < 2; ++p) {
    const int cl = r + p * 32;
    if (mode == MODE_F32)   // bf16 canonical copy needed only in F32 mode
      *(bf16x8*)(g_q + base + (size_t)(c0 + cl) * N_ + n0 + co) = v[p];
    const int swz = nb ^ ((cl >> 3) & 7);
    *(bf16x8*)(&Ts[cl][swz * 8]) = v[p];
  }
  __syncthreads();

  // transposed read: QT[b][n0+nl][c0+co .. +7]
#pragma unroll
  for (int p = 0; p < 2; ++p) {
    const int nl = r + p * 32;
    bf16x8 w;
#pragma unroll
    for (int j = 0; j < 8; ++j) {
      const int c = co + j;
      const int k = (c >> 3) & 7;   // == nb
      w[j] = Ts[c][(((nl >> 3) ^ k) * 8) + (nl & 7)];
    }
    *(bf16x8*)(g_qT + (size_t)b * N_ * C_ + (size_t)(n0 + nl) * C_ + c0 + co) = w;
  }
}

// ---------------------------------------------------------------------------
// Kernel 1: Ep[kc][s][b][c][d] = sum_{n in chunk} Q[b,c,n] * Ksrc_s[b,d,n]
// 128x128 tile, 4 waves of 64x64, BK=64, reg-staged padded LDS, K split x4,
// 2-deep register prefetch (T14). 1D grid 768, XCD-chunked swizzle.
// ---------------------------------------------------------------------------
#define E_LOAD(av, bv, k0)                                                     \
  {                                                                            \
    _Pragma("unroll")                                                          \
    for (int i = 0; i < 4; ++i) {                                              \
      int r = srow + i * 32;                                                   \
      av[i] = *(const bf16x8*)(q + (size_t)(tile_m + r) * N_ + (k0) + soff);   \
    }                                                                          \
    if (kf32) {                                                                \
      _Pragma("unroll")                                                        \
      for (int i = 0; i < 4; ++i) {                                            \
        int r = srow + i * 32;                                                 \
        const float* sp = kf32 + (size_t)(tile_d + r) * N_ + (k0) + soff;      \
        float4 a4 = *(const float4*)sp;                                        \
        float4 c4 = *(const float4*)(sp + 4);                                  \
        bf16x8 vv;                                                             \
        vv[0] = (bf16_t)a4.x; vv[1] = (bf16_t)a4.y;                            \
        vv[2] = (bf16_t)a4.z; vv[3] = (bf16_t)a4.w;                            \
        vv[4] = (bf16_t)c4.x; vv[5] = (bf16_t)c4.y;                            \
        vv[6] = (bf16_t)c4.z; vv[7] = (bf16_t)c4.w;                            \
        bv[i] = vv;                                                            \
      }                                                                        \
    } else {                                                                   \
      _Pragma("unroll")                                                        \
      for (int i = 0; i < 4; ++i) {                                            \
        int r = srow + i * 32;                                                 \
        bv[i] = *(const bf16x8*)(kb16 + (size_t)(tile_d + r) * N_ + (k0) + soff); \
      }                                                                        \
    }                                                                          \
  }

#define E_STORE(av, bv)                                                        \
  {                                                                            \
    _Pragma("unroll")                                                          \
    for (int i = 0; i < 4; ++i) {                                              \
      int r = srow + i * 32;                                                   \
      *(bf16x8*)(&As[r][soff]) = av[i];                                        \
      *(bf16x8*)(&Bs[r][soff]) = bv[i];                                        \
    }                                                                          \
  }

#define E_MFMA()                                                               \
  {                                                                            \
    _Pragma("unroll")                                                          \
    for (int kk = 0; kk < 64; kk += 32) {                                      \
      bf16x8 af[4], bfr[4];                                                    \
      _Pragma("unroll")                                                        \
      for (int i = 0; i < 4; ++i)                                              \
        af[i] = *(const bf16x8*)(&As[wm + i * 16 + lrow][kk + lk]);            \
      _Pragma("unroll")                                                        \
      for (int j = 0; j < 4; ++j)                                              \
        bfr[j] = *(const bf16x8*)(&Bs[wd + j * 16 + lrow][kk + lk]);           \
      _Pragma("unroll")                                                        \
      for (int i = 0; i < 4; ++i)                                              \
        _Pragma("unroll")                                                      \
        for (int j = 0; j < 4; ++j)                                            \
          acc[i][j] = MFMA(af[i], bfr[j], acc[i][j]);                          \
    }                                                                          \
  }

__global__ __launch_bounds__(256) void energy_kernel(
    const void* __restrict__ xraw, const void* __restrict__ yraw,
    const void* __restrict__ zraw)
{
  const int id   = blockIdx.x;                 // 0..767
  const int swz  = (id & 7) * 96 + (id >> 3);  // XCD x gets [x*96, x*96+96)
  const int tile = swz & 3;                    // 0..3
  const int s    = (swz >> 2) % 3;             // 0..2
  const int kc   = (swz / 12) & 3;             // 0..3
  const int b    = swz / 48;                   // 0..15

  const int mode = g_mode;
  const bf16_t* q =
      (mode == MODE_BF16 ? (const bf16_t*)xraw : g_q) + (size_t)b * C_ * N_;

  const bf16_t* kb16 = nullptr;
  const float*  kf32 = nullptr;
  if (s == 0) {
    kb16 = q;
  } else if (mode == MODE_BF16) {
    kb16 = (const bf16_t*)(s == 1 ? yraw : zraw) + (size_t)b * C_ * N_;
  } else {
    kf32 = (const float*)(s == 1 ? yraw : zraw) + (size_t)b * C_ * N_;
  }

  const int tile_m = (tile & 1) * 128;
  const int tile_d = (tile >> 1) * 128;

  __shared__ bf16_t As[128][72];  // stride 144 B: 16B-aligned rows, non-pow2
  __shared__ bf16_t Bs[128][72];

  const int tid  = threadIdx.x;
  const int w    = tid >> 6;
  const int lane = tid & 63;
  const int wm   = (w & 1) * 64;
  const int wd   = (w >> 1) * 64;
  const int lrow = lane & 15;
  const int lk   = (lane >> 4) * 8;

  const int srow = tid >> 3;        // 0..31
  const int soff = (tid & 7) * 8;   // 0..56

  f32x4 acc[4][4] = {};

  const int kbeg = kc * KCHUNK;
  const int kend = kbeg + KCHUNK;

  bf16x8 avA[4], bvA[4], avB[4], bvB[4];
  E_LOAD(avA, bvA, kbeg);           // prologue

  // KCHUNK/64 = 16 half-steps = 8 double-iterations
  for (int k0 = kbeg; k0 < kend; k0 += 128) {
    // half-step A: prefetch k0+64 early, stage regs A, compute
    __syncthreads();                 // prior MFMA LDS reads done
    E_LOAD(avB, bvB, k0 + 64);       // issue-early (always in range)
    E_STORE(avA, bvA);               // waits only on A-loads (1 phase old)
    __syncthreads();
    E_MFMA();
    // half-step B: prefetch k0+128 (guarded, uniform), stage regs B, compute
    __syncthreads();
    if (k0 + 128 < kend) { E_LOAD(avA, bvA, k0 + 128); }
    E_STORE(avB, bvB);
    __syncthreads();
    E_MFMA();
  }

  // C/D layout: col = lane&15, row = (lane>>4)*4 + r
  float* Eb = g_Ep + (((size_t)kc * 3 + s) * B_ + b) * (size_t)C_ * C_;
  const int orow0 = tile_m + wm + (lane >> 4) * 4;
  const int ocol0 = tile_d + wd + (lane & 15);
#pragma unroll
  for (int i = 0; i < 4; ++i)
#pragma unroll
    for (int j = 0; j < 4; ++j)
#pragma unroll
      for (int r = 0; r < 4; ++r)
        Eb[(size_t)(orow0 + i * 16 + r) * C_ + (ocol0 + j * 16)] = acc[i][j][r];
}

// ---------------------------------------------------------------------------
// Kernel 2: attnT[b][d][c] = sum_s exp(min_d E_s - E_s[c,d]) / Z_s   (bf16)
// One wave per c-row (4 rows/block), shuffle reductions, sums KSPLIT partials.
// grid (C/4, B).
// ---------------------------------------------------------------------------
__global__ __launch_bounds__(256) void softmax_kernel()
{
  const int b    = blockIdx.y;
  const int c    = blockIdx.x * 4 + (threadIdx.x >> 6);
  const int lane = threadIdx.x & 63;
  const int d0   = lane * 4;

  float a0 = 0.f, a1 = 0.f, a2 = 0.f, a3 = 0.f;
#pragma unroll
  for (int s = 0; s < 3; ++s) {
    float e0 = 0.f, e1 = 0.f, e2 = 0.f, e3 = 0.f;
#pragma unroll
    for (int kc = 0; kc < KSPLIT; ++kc) {
      const float4 ep = *(const float4*)(
          g_Ep + ((((size_t)kc * 3 + s) * B_ + b) * C_ + c) * (size_t)C_ + d0);
      e0 += ep.x; e1 += ep.y; e2 += ep.z; e3 += ep.w;
    }
    float mn = fminf(fminf(e0, e1), fminf(e2, e3));
#pragma unroll
    for (int m = 32; m > 0; m >>= 1) mn = fminf(mn, __shfl_xor(mn, m));
    const float p0 = __expf(mn - e0);   // <= 1; min term gives exactly 1
    const float p1 = __expf(mn - e1);
    const float p2 = __expf(mn - e2);
    const float p3 = __expf(mn - e3);
    float Z = p0 + p1 + p2 + p3;
#pragma unroll
    for (int m = 32; m > 0; m >>= 1) Z += __shfl_xor(Z, m);
    const float rZ = 1.0f / Z;
    a0 += p0 * rZ; a1 += p1 * rZ; a2 += p2 * rZ; a3 += p3 * rZ;
  }
  bf16_t* At = g_attnT + (size_t)b * C_ * C_;   // [d][c], transposed for mconv
  At[(size_t)(d0 + 0) * C_ + c] = (bf16_t)a0;
  At[(size_t)(d0 + 1) * C_ + c] = (bf16_t)a1;
  At[(size_t)(d0 + 2) * C_ + c] = (bf16_t)a2;
  At[(size_t)(d0 + 3) * C_ + c] = (bf16_t)a3;
}

// ---------------------------------------------------------------------------
// Kernel 3: M[b][o][d] = sum_c conv_w[o,c] * attnT[b][d][c]   (bf16 out)
// 64x64 tiles, 4 waves of 32x32, grid (16, B) = 256 blocks (1/CU).
// ---------------------------------------------------------------------------
__global__ __launch_bounds__(256) void mconv_kernel()
{
  const int tile = blockIdx.x;  // 0..15
  const int b    = blockIdx.y;
  const int tile_o = (tile & 3) * 64;
  const int tile_d = (tile >> 2) * 64;
  const int tid  = threadIdx.x;
  const int w    = tid >> 6;
  const int lane = tid & 63;
  const int wo   = (w & 1) * 32;
  const int wd   = (w >> 1) * 32;
  const int lrow = lane & 15;
  const int lk   = (lane >> 4) * 8;

  const bf16_t* At = g_attnT + (size_t)b * C_ * C_;
  f32x4 acc[2][2] = {};

  for (int c0 = 0; c0 < C_; c0 += 32) {
    bf16x8 af[2], bfr[2];
#pragma unroll
    for (int i = 0; i < 2; ++i)
      af[i] = *(const bf16x8*)(g_cw + (size_t)(tile_o + wo + i * 16 + lrow) * C_ + c0 + lk);
#pragma unroll
    for (int j = 0; j < 2; ++j)
      bfr[j] = *(const bf16x8*)(At + (size_t)(tile_d + wd + j * 16 + lrow) * C_ + c0 + lk);
#pragma unroll
    for (int i = 0; i < 2; ++i)
#pragma unroll
      for (int j = 0; j < 2; ++j)
        acc[i][j] = MFMA(af[i], bfr[j], acc[i][j]);
  }

  bf16_t* Mb = g_M + (size_t)b * C_ * C_;
  const int orow0 = tile_o + wo + (lane >> 4) * 4;
  const int ocol0 = tile_d + wd + (lane & 15);
#pragma unroll
  for (int i = 0; i < 2; ++i)
#pragma unroll
    for (int j = 0; j < 2; ++j)
#pragma unroll
      for (int r = 0; r < 4; ++r)
        Mb[(size_t)(orow0 + i * 16 + r) * C_ + (ocol0 + j * 16)] = (bf16_t)acc[i][j][r];
}

// ---------------------------------------------------------------------------
// Kernel 4: P-tile = M @ Q^T with FUSED epilogue + 2-deep prefetch.
//   out[b][o][n] = gamma*(bf16(acc) + bias[o]) + x[b][o][n]
// 1D grid 1024, XCD-chunked swizzle. Dynamic LDS = 36864 B.
// ---------------------------------------------------------------------------
#define P_LOAD(av, bv, d0)                                                     \
  {                                                                            \
    _Pragma("unroll")                                                          \
    for (int i = 0; i < 4; ++i) {                                              \
      int r = srow + i * 32;                                                   \
      av[i] = *(const bf16x8*)(Mb + (size_t)(tile_o + r) * C_ + (d0) + soff);  \
      bv[i] = *(const bf16x8*)(Qt + (size_t)(tile_n + r) * C_ + (d0) + soff);  \
    }                                                                          \
  }

#define P_STORE(av, bv)                                                        \
  {                                                                            \
    _Pragma("unroll")                                                          \
    for (int i = 0; i < 4; ++i) {                                              \
      int r = srow + i * 32;                                                   \
      *(bf16x8*)(&As[r][soff]) = av[i];                                        \
      *(bf16x8*)(&Bs[r][soff]) = bv[i];                                        \
    }                                                                          \
  }

#define P_MFMA()                                                               \
  {                                                                            \
    _Pragma("unroll")                                                          \
    for (int kk = 0; kk < 64; kk += 32) {                                      \
      bf16x8 af[4], bfr[4];                                                    \
      _Pragma("unroll")                                                        \
      for (int i = 0; i < 4; ++i)                                              \
        af[i] = *(const bf16x8*)(&As[wo + i * 16 + lrow][kk + lk]);            \
      _Pragma("unroll")                                                        \
      for (int j = 0; j < 4; ++j)                                              \
        bfr[j] = *(const bf16x8*)(&Bs[wn + j * 16 + lrow][kk + lk]);           \
      _Pragma("unroll")                                                        \
      for (int i = 0; i < 4; ++i)                                              \
        _Pragma("unroll")                                                      \
        for (int j = 0; j < 4; ++j)                                            \
          acc[i][j] = MFMA(af[i], bfr[j], acc[i][j]);                          \
    }                                                                          \
  }

__global__ __launch_bounds__(256) void pmq_kernel(
    const void* __restrict__ xraw, void* __restrict__ outraw)
{
  extern __shared__ char smraw[];
  bf16_t* sm = (bf16_t*)smraw;
  bf16_t (*As)[72]  = (bf16_t(*)[72])sm;              // [128][72] M rows
  bf16_t (*Bs)[72]  = (bf16_t(*)[72])(sm + 128 * 72); // [128][72] qT rows
  bf16_t (*Os)[136] = (bf16_t(*)[136])sm;             // [128][136] out tile (reuse)

  const int id  = blockIdx.x;                  // 0..1023
  const int swz = (id & 7) * 128 + (id >> 3);  // XCD-chunked
  const int tile_o = (swz & 1) * 128;
  const int tile_n = ((swz >> 1) & 31) * 128;
  const int b      = swz >> 6;

  const bf16_t* Mb = g_M  + (size_t)b * C_ * C_;
  const bf16_t* Qt = g_qT + (size_t)b * N_ * C_;

  const int tid  = threadIdx.x;
  const int w    = tid >> 6;
  const int lane = tid & 63;
  const int wo   = (w & 1) * 64;
  const int wn   = (w >> 1) * 64;
  const int lrow = lane & 15;
  const int lk   = (lane >> 4) * 8;

  const int srow = tid >> 3;        // 0..31
  const int soff = (tid & 7) * 8;   // 0..56

  f32x4 acc[4][4] = {};

  bf16x8 avA[4], bvA[4], avB[4], bvB[4];
  P_LOAD(avA, bvA, 0);              // prologue

  // C_/64 = 4 half-steps = 2 double-iterations
  for (int d0 = 0; d0 < C_; d0 += 128) {
    __syncthreads();
    P_LOAD(avB, bvB, d0 + 64);
    P_STORE(avA, bvA);
    __syncthreads();
    P_MFMA();
    __syncthreads();
    if (d0 + 128 < C_) { P_LOAD(avA, bvA, d0 + 128); }
    P_STORE(avB, bvB);
    __syncthreads();
    P_MFMA();
  }

  // ---- fused epilogue ----
  __syncthreads();   // all waves done with As/Bs before aliasing as Os

  // scatter acc (bf16-rounded, same rounding point as the old P store)
  const int orow0 = wo + (lane >> 4) * 4;   // local row in 128-tile
  const int ocol0 = wn + (lane & 15);
#pragma unroll
  for (int i = 0; i < 4; ++i)
#pragma unroll
    for (int j = 0; j < 4; ++j)
#pragma unroll
      for (int r = 0; r < 4; ++r)
        Os[orow0 + i * 16 + r][ocol0 + j * 16] = (bf16_t)acc[i][j][r];
  __syncthreads();

  // coalesced read-back: pass p covers rows p*16 + (tid>>4), 16 lanes span a
  // 256 B row segment (16B/lane).
  const float g   = g_gamma;
  const int mode  = g_mode;
  const int rr    = tid >> 4;          // 0..15
  const int cc    = (tid & 15) * 8;    // 0..120
  const size_t gbase = (size_t)b * C_ * N_;

#pragma unroll
  for (int p = 0; p < 8; ++p) {
    const int r = p * 16 + rr;
    const float bias = g_cb[tile_o + r];
    const bf16x8 sv = *(const bf16x8*)(&Os[r][cc]);
    const size_t off = gbase + (size_t)(tile_o + r) * N_ + tile_n + cc;
    if (mode == MODE_F32) {
      const float* xp = (const float*)xraw + off;
      float*       op = (float*)outraw + off;
#pragma unroll
      for (int q4 = 0; q4 < 2; ++q4) {
        float4 xv = *(const float4*)(xp + q4 * 4);
        float4 ov;
        ov.x = g * ((float)sv[q4 * 4 + 0] + bias) + xv.x;
        ov.y = g * ((float)sv[q4 * 4 + 1] + bias) + xv.y;
        ov.z = g * ((float)sv[q4 * 4 + 2] + bias) + xv.z;
        ov.w = g * ((float)sv[q4 * 4 + 3] + bias) + xv.w;
        *(float4*)(op + q4 * 4) = ov;
      }
    } else {
      const bf16_t* xp = (const bf16_t*)xraw + off;
      bf16_t*       op = (bf16_t*)outraw + off;
      const bf16x8 xv = *(const bf16x8*)xp;
      bf16x8 ov;
#pragma unroll
      for (int k = 0; k < 8; ++k)
        ov[k] = (bf16_t)(g * ((float)sv[k] + bias) + (float)xv[k]);
      *(bf16x8*)op = ov;
    }
  }
}

// ---------------------------------------------------------------------------
extern "C" void kernel_launch(void* const* d_in, const int* in_sizes, int n_in,
                              void* d_out, int out_size, void* d_ws, size_t ws_size,
                              hipStream_t stream)
{
  const void* x  = d_in[0];
  const void* y  = d_in[1];
  const void* z  = d_in[2];
  const void* cw = d_in[3];
  const void* cb = d_in[4];
  const void* gm = d_in[5];
  (void)d_ws; (void)ws_size;

  setup_kernel   <<<1,                          256, 0, stream>>>((const float*)x, cw, cb, gm);
  convert_xT     <<<dim3(N_ / 64, C_ / 64, B_), 256, 0, stream>>>(x);
  energy_kernel  <<<dim3(4 * KSPLIT * 3 * B_),  256, 0, stream>>>(x, y, z);
  softmax_kernel <<<dim3(C_ / 4, B_),           256, 0, stream>>>();
  mconv_kernel   <<<dim3(16, B_),               256, 0, stream>>>();
  pmq_kernel     <<<dim3(N_ / 128 * 2 * B_),    256, 36864, stream>>>(x, d_out);
}